// Round 5
// baseline (50244.888 us; speedup 1.0000x reference)
//
#include <hip/hip_runtime.h>

#define V 32000
#define D 256
#define H 256
#define T 128
#define B 32
#define SOS 126
#define H2 512

#define NBLK 512
#define NTHR 256
#define SCOPE __HIP_MEMORY_SCOPE_AGENT
#define LDS_FLOATS 19456   // 18432 x-slab + 1024 scratch = 77824 B (2 blocks/CU)
#define S0 18432           // scratch base (floats)

__device__ __forceinline__ float sigf(float x) { return 1.f / (1.f + __expf(-x)); }
__device__ __forceinline__ float ftanh(float x) {
    x = fminf(15.f, fmaxf(-15.f, x));
    float e = __expf(2.f * x);
    return (e - 1.f) / (e + 1.f);
}

// ---- agent-scope (L2-bypassing, L3-coherent) scalar load/store
__device__ __forceinline__ float lda(const float* p) {
    return __hip_atomic_load(p, __ATOMIC_RELAXED, SCOPE);
}
__device__ __forceinline__ void sta(float* p, float v) {
    __hip_atomic_store(p, v, __ATOMIC_RELAXED, SCOPE);
}
__device__ __forceinline__ int ldai(const int* p) {
    return __hip_atomic_load(p, __ATOMIC_RELAXED, SCOPE);
}
__device__ __forceinline__ void stai(int* p, int v) {
    __hip_atomic_store(p, v, __ATOMIC_RELAXED, SCOPE);
}

// ---------------- store-based grid barrier. light = no cache maintenance
// (all cross-block data uses agent ops); heavy = full release/acquire fences
// for normally-cached handoffs (used twice total).
__device__ __forceinline__ void gbar(int* __restrict__ slots, int* __restrict__ gen,
                                     int tgt, bool heavy) {
    __syncthreads();   // drains each wave's vmcnt before s_barrier (HIP semantics)
    if (threadIdx.x == 0) {
        if (heavy) __builtin_amdgcn_fence(__ATOMIC_RELEASE, "agent");
        stai(slots + (size_t)blockIdx.x * 32, tgt);
    }
    if (blockIdx.x == 0) {
        int i0 = (int)threadIdx.x * 2;
        unsigned g1 = 0;
        while (ldai(slots + (size_t)i0 * 32) < tgt) {
            __builtin_amdgcn_s_sleep(1);
            if (++g1 > 100000000u) break;   // safety: garbage > hang
        }
        g1 = 0;
        while (ldai(slots + (size_t)(i0 + 1) * 32) < tgt) {
            __builtin_amdgcn_s_sleep(1);
            if (++g1 > 100000000u) break;
        }
        asm volatile("" ::: "memory");
        __syncthreads();
        if (threadIdx.x == 0) stai(gen, tgt);
    } else {
        if (threadIdx.x == 0) {
            unsigned gd = 0;
            while (ldai(gen) < tgt) {
                __builtin_amdgcn_s_sleep(4);
                if (++gd > 100000000u) break;
            }
            asm volatile("" ::: "memory");
        }
    }
    if (heavy && threadIdx.x == 0) __builtin_amdgcn_fence(__ATOMIC_ACQUIRE, "agent");
    __syncthreads();
}

// ---------------- generic LDS-tiled transpose: dst[C][R] from src[R][C]
__global__ __launch_bounds__(256) void k_tr(const float* __restrict__ src,
                                            float* __restrict__ dst, int R, int C) {
    __shared__ float tle[32][33];
    int rb = blockIdx.x * 32, cb = blockIdx.y * 32;
    int lr = threadIdx.x & 31, lc = threadIdx.x >> 5;
#pragma unroll
    for (int i = 0; i < 32; i += 8) tle[lc + i][lr] = src[(size_t)(rb + lc + i) * C + cb + lr];
    __syncthreads();
#pragma unroll
    for (int i = 0; i < 32; i += 8) dst[(size_t)(cb + lc + i) * R + rb + lr] = tle[lr][lc + i];
}

// ---------------- WencT[k][dir*1024 + u*4+g]
__global__ __launch_bounds__(256) void k_prep_encw(
    const float* __restrict__ Wih_f, const float* __restrict__ Whh_f,
    const float* __restrict__ Wih_b, const float* __restrict__ Whh_b,
    float* __restrict__ WencT) {
    int idx = blockIdx.x * 256 + threadIdx.x;     // 512*2048
    int k = idx >> 11, col = idx & 2047;
    int dir = col >> 10, cu = col & 1023;
    int u = cu >> 2, g = cu & 3;
    const float* Wih = dir ? Wih_b : Wih_f;
    const float* Whh = dir ? Whh_b : Whh_f;
    float v = (k < 256) ? Wih[(g * H + u) * D + k] : Whh[(g * H + u) * H + (k - 256)];
    WencT[idx] = v;
}

// ---------------- WdT[k][u*4+g]
__global__ __launch_bounds__(256) void k_prep_decw(const float* __restrict__ Wih_d,
                                                   const float* __restrict__ Whh_d,
                                                   float* __restrict__ WdT) {
    int idx = blockIdx.x * 256 + threadIdx.x;     // 1280*2048
    int k = idx >> 11, col = idx & 2047;
    int u = col >> 2, g = col & 3;
    float v = (k < 768) ? Wih_d[(size_t)(g * H2 + u) * 768 + k]
                        : Whh_d[(size_t)(g * H2 + u) * H2 + (k - 768)];
    WdT[idx] = v;
}

// ---------------- final: out = logits - lse[b*T+t]
__global__ __launch_bounds__(256) void k_norm(float* __restrict__ out,
                                              const float* __restrict__ lse) {
    const int total4 = B * T * V / 4;
    int stride = gridDim.x * 256;
    for (int i4 = blockIdx.x * 256 + threadIdx.x; i4 < total4; i4 += stride) {
        int rowv = i4 / (V / 4);
        float l = lse[rowv];
        float4* p = (float4*)out + i4;
        float4 v = *p;
        v.x -= l; v.y -= l; v.z -= l; v.w -= l;
        *p = v;
    }
}

// ==================== THE PERSISTENT KERNEL ====================
__global__ __launch_bounds__(256, 2) void k_seq(
    const int* __restrict__ x, const float* __restrict__ emb_enc,
    const float* __restrict__ emb_dec,
    const float* __restrict__ bih_f, const float* __restrict__ bhh_f,
    const float* __restrict__ bih_b, const float* __restrict__ bhh_b,
    const float* __restrict__ bih_d, const float* __restrict__ bhh_d,
    const float* __restrict__ Wa_e, const float* __restrict__ Wa_h,
    const float* __restrict__ b_a, const float* __restrict__ v_a,
    const float* __restrict__ bout,
    const float* __restrict__ WencT, const float* __restrict__ WdT,
    const float* __restrict__ WoutT, const float* __restrict__ WahT,
    float* __restrict__ enc_out, float* __restrict__ proj_e,
    float* __restrict__ zpenc,
    float* __restrict__ hdecT, float* __restrict__ cdecT,
    float* __restrict__ xcatT, float* __restrict__ q_buf, float* __restrict__ zp_h,
    float* __restrict__ Pm, float* __restrict__ Ps,
    int* __restrict__ Pi, float* __restrict__ lse, float* __restrict__ out,
    int* slots, int* gen) {
    extern __shared__ float xs[];
    const int blk = blockIdx.x, tid = threadIdx.x;
    const int kc = (tid >> 3) & 7;
    const int rp = (tid >> 6) * 8 + (tid & 7);   // 0..31
    int bgen = 0;
    float c_priv[16];                            // encoder cell state (c==1 blocks)

    // ===================== ENCODER =====================
    for (int t = 0; t <= T; ++t) {
        if (blk < 128) {
            int rowgrp = blk >> 2, c = (blk >> 1) & 1, bh = blk & 1;
            int dir = rowgrp >> 4;
            // ---- stage
            if (c == 0) {
                if (t < T) {
                    for (int i = tid; i < 4096; i += 256) {
                        int bb = i >> 8, k = i & 255;
                        int tok = x[(bh * 16 + bb) * T + t];
                        xs[k * 20 + bb] = emb_enc[tok * 256 + k];
                    }
                }
            } else {
                if (t == 0) {
#pragma unroll
                    for (int j = 0; j < 16; ++j) {
                        int i = tid + j * 256;
                        int u = i >> 4, bb = i & 15;
                        xs[u * 20 + bb] = 0.f;
                        c_priv[j] = 0.f;
                    }
                } else {
                    bool writer = (rowgrp & 15) == 0;
                    const float* zpp = zpenc + ((t - 1) & 1) * 131072;
#pragma unroll
                    for (int j = 0; j < 16; ++j) {
                        int i = tid + j * 256;
                        int u = i >> 4, bb = i & 15, bG = bh * 16 + bb;
                        int r = dir * 1024 + u * 4;
                        float z[4];
#pragma unroll
                        for (int g = 0; g < 4; ++g) {
                            float bias = (dir ? bih_b : bih_f)[g * 256 + u] +
                                         (dir ? bhh_b : bhh_f)[g * 256 + u];
                            z[g] = lda(zpp + (size_t)(r + g) * 32 + bG) +
                                   lda(zpp + (size_t)(2048 + r + g) * 32 + bG) + bias;
                        }
                        float cp = c_priv[j];
                        float c2 = sigf(z[1]) * cp + sigf(z[0]) * ftanh(z[2]);
                        float h2 = sigf(z[3]) * ftanh(c2);
                        c_priv[j] = c2;
                        xs[u * 20 + bb] = h2;
                        if (writer) {
                            enc_out[(size_t)(bG * T + (t - 1)) * H2 + dir * 256 + u] = h2;
                            if (t == T) {
                                hdecT[(dir * 256 + u) * 32 + bG] = h2;
                                cdecT[(dir * 256 + u) * 32 + bG] = c2;
                            }
                        }
                    }
                }
            }
            __syncthreads();
            // ---- mm -> zpenc[t&1][c]
            if (t < T) {
                int r0 = rowgrp * 64 + rp * 2;
                float a0[16], a1[16];
#pragma unroll
                for (int j = 0; j < 16; ++j) { a0[j] = 0.f; a1[j] = 0.f; }
#pragma unroll 4
                for (int j = 0; j < 32; ++j) {
                    int kl = kc + 8 * j;
                    float2 w = *(const float2*)(WencT + (size_t)(c * 256 + kl) * 2048 + r0);
                    const float* xp = xs + kl * 20;
#pragma unroll
                    for (int q = 0; q < 4; ++q) {
                        float4 xv = *(const float4*)(xp + q * 4);
                        a0[q*4+0] = fmaf(w.x, xv.x, a0[q*4+0]); a1[q*4+0] = fmaf(w.y, xv.x, a1[q*4+0]);
                        a0[q*4+1] = fmaf(w.x, xv.y, a0[q*4+1]); a1[q*4+1] = fmaf(w.y, xv.y, a1[q*4+1]);
                        a0[q*4+2] = fmaf(w.x, xv.z, a0[q*4+2]); a1[q*4+2] = fmaf(w.y, xv.z, a1[q*4+2]);
                        a0[q*4+3] = fmaf(w.x, xv.w, a0[q*4+3]); a1[q*4+3] = fmaf(w.y, xv.w, a1[q*4+3]);
                    }
                }
#pragma unroll
                for (int j = 0; j < 16; ++j) {
                    a0[j] += __shfl_xor(a0[j], 8); a0[j] += __shfl_xor(a0[j], 16); a0[j] += __shfl_xor(a0[j], 32);
                    a1[j] += __shfl_xor(a1[j], 8); a1[j] += __shfl_xor(a1[j], 16); a1[j] += __shfl_xor(a1[j], 32);
                }
                if (((tid >> 3) & 7) == 0) {
                    float* zb = zpenc + (t & 1) * 131072 + (size_t)(c * 2048 + r0) * 32 + bh * 16;
#pragma unroll
                    for (int q = 0; q < 16; ++q) {
                        sta(zb + q, a0[q]);
                        sta(zb + 32 + q, a1[q]);
                    }
                }
            }
        }
        ++bgen; gbar(slots, gen, bgen, t == T);   // heavy at t==T (publish enc_out/hdecT/cdecT)
    }

    // ===================== pre-decoder: proj_e + q0 (normal ld/st) =====================
    {
        if (blk < 256) {
            int r0 = blk * 16;
            for (int i = tid; i < 16 * 512; i += 256) {
                int r = i >> 9, k = i & 511;
                xs[r * 512 + k] = enc_out[(size_t)(r0 + r) * H2 + k];
            }
            __syncthreads();
            int j0 = tid * 2;
            float acc0[16], acc1[16];
#pragma unroll
            for (int r = 0; r < 16; ++r) { acc0[r] = 0.f; acc1[r] = 0.f; }
            const float* w0 = Wa_e + j0 * H2;
            const float* w1 = Wa_e + (j0 + 1) * H2;
            for (int k = 0; k < H2; k += 4) {
                float4 wa = *(const float4*)(w0 + k);
                float4 wb = *(const float4*)(w1 + k);
#pragma unroll
                for (int r = 0; r < 16; ++r) {
                    float4 xv = *(const float4*)(&xs[r * 512 + k]);
                    acc0[r] = fmaf(wa.x, xv.x, acc0[r]); acc0[r] = fmaf(wa.y, xv.y, acc0[r]);
                    acc0[r] = fmaf(wa.z, xv.z, acc0[r]); acc0[r] = fmaf(wa.w, xv.w, acc0[r]);
                    acc1[r] = fmaf(wb.x, xv.x, acc1[r]); acc1[r] = fmaf(wb.y, xv.y, acc1[r]);
                    acc1[r] = fmaf(wb.z, xv.z, acc1[r]); acc1[r] = fmaf(wb.w, xv.w, acc1[r]);
                }
            }
#pragma unroll
            for (int r = 0; r < 16; ++r) {
                float2 st; st.x = acc0[r]; st.y = acc1[r];
                *(float2*)(proj_e + (size_t)(r0 + r) * H2 + j0) = st;
            }
        } else if (blk < 320) {
            int gi = (blk - 256) * 256 + tid;
            int j = gi >> 5, b = gi & 31;
            float a0 = 0, a1 = 0, a2 = 0, a3 = 0;
            const float* wr = Wa_h + (size_t)j * H2;
            for (int k = 0; k < H2; k += 4) {
                float4 w = *(const float4*)(wr + k);
                a0 = fmaf(w.x, hdecT[(k    ) * 32 + b], a0);
                a1 = fmaf(w.y, hdecT[(k + 1) * 32 + b], a1);
                a2 = fmaf(w.z, hdecT[(k + 2) * 32 + b], a2);
                a3 = fmaf(w.w, hdecT[(k + 3) * 32 + b], a3);
            }
            q_buf[b * H2 + j] = (a0 + a1) + (a2 + a3);
        }
    }
    ++bgen; gbar(slots, gen, bgen, true);   // heavy (publish proj_e/q_buf)

    // ===================== DECODER =====================
    for (int t = 0; t < T; ++t) {
        // ---------- phA: attention pipeline (0..31) || Whh x h_{t-1} (64..127)
        if (blk < 32) {
            int b = blk;
            int tok = SOS;
            if (t > 0) {
                float* rm = xs + S0; float* rs = rm + 256; int* ri = (int*)(rs + 256);
                float m = -INFINITY, s = 0.f; int mi = 0x7fffffff;
                for (int i = tid; i < 512; i += 256) {
                    if (i < 500) {
                        float m2 = lda(Pm + b * 512 + i), s2 = lda(Ps + b * 512 + i);
                        int i2 = ldai(Pi + b * 512 + i);
                        if (m2 > m)      { s = s2 + s * __expf(m - m2); m = m2; mi = i2; }
                        else if (m > m2) { s = s + s2 * __expf(m2 - m); }
                        else             { s = s + s2; mi = (mi < i2) ? mi : i2; }
                    }
                }
                rm[tid] = m; rs[tid] = s; ri[tid] = mi;
                __syncthreads();
                for (int off = 128; off >= 1; off >>= 1) {
                    if (tid < off) {
                        float m1 = rm[tid], m2 = rm[tid + off];
                        float s1 = rs[tid], s2 = rs[tid + off];
                        int i1 = ri[tid], i2 = ri[tid + off];
                        float m_, s_; int i_;
                        if (m2 > m1)      { m_ = m2; s_ = s2 + s1 * __expf(m1 - m2); i_ = i2; }
                        else if (m1 > m2) { m_ = m1; s_ = s1 + s2 * __expf(m2 - m1); i_ = i1; }
                        else              { m_ = m1; s_ = s1 + s2; i_ = (i1 < i2) ? i1 : i2; }
                        rm[tid] = m_; rs[tid] = s_; ri[tid] = i_;
                    }
                    __syncthreads();
                }
                if (tid == 0) lse[b * T + (t - 1)] = rm[0] + logf(rs[0]);
                __syncthreads();
                tok = ri[0];
            }
            // embedding -> xcatT rows [0,256)
            sta(xcatT + tid * 32 + b, emb_dec[tok * 256 + tid]);
            // energy -> es (LDS)
            float* es = xs + S0;
            {
                int l = tid & 63, w = tid >> 6;
                float q8[8], va8[8];
                const float* qp = q_buf + b * H2 + l * 8;
#pragma unroll
                for (int j = 0; j < 8; ++j) {
                    q8[j] = lda(qp + j) + b_a[l * 8 + j];
                    va8[j] = v_a[l * 8 + j];
                }
                for (int tt = w; tt < T; tt += 4) {
                    const float* pp = proj_e + (size_t)(b * T + tt) * H2 + l * 8;
                    float4 p0 = *(const float4*)(pp);
                    float4 p1 = *(const float4*)(pp + 4);
                    float s = ftanh(p0.x + q8[0]) * va8[0] + ftanh(p0.y + q8[1]) * va8[1]
                            + ftanh(p0.z + q8[2]) * va8[2] + ftanh(p0.w + q8[3]) * va8[3]
                            + ftanh(p1.x + q8[4]) * va8[4] + ftanh(p1.y + q8[5]) * va8[5]
                            + ftanh(p1.z + q8[6]) * va8[6] + ftanh(p1.w + q8[7]) * va8[7];
#pragma unroll
                    for (int off = 32; off >= 1; off >>= 1) s += __shfl_xor(s, off);
                    if (l == 0) es[tt] = s;
                }
            }
            __syncthreads();
            // softmax over T=128
            float* red = xs + S0 + 128; float* wsm = xs + S0 + 256;
            if (tid < 128) red[tid] = es[tid];
            __syncthreads();
            for (int off = 64; off >= 1; off >>= 1) {
                if (tid < off) red[tid] = fmaxf(red[tid], red[tid + off]);
                __syncthreads();
            }
            float M = red[0];
            __syncthreads();
            float ev = 0.f;
            if (tid < 128) { ev = __expf(es[tid] - M); red[tid] = ev; }
            __syncthreads();
            for (int off = 64; off >= 1; off >>= 1) {
                if (tid < off) red[tid] += red[tid + off];
                __syncthreads();
            }
            float S = red[0];
            __syncthreads();
            if (tid < 128) wsm[tid] = ev / S;
            __syncthreads();
            // ctx -> xcatT rows [256,768)
            float acc0 = 0.f, acc1 = 0.f;
            const float* eo = enc_out + (size_t)b * T * H2;
#pragma unroll 8
            for (int t2 = 0; t2 < T; ++t2) {
                float wv = wsm[t2];
                acc0 = fmaf(wv, eo[t2 * H2 + tid], acc0);
                acc1 = fmaf(wv, eo[t2 * H2 + tid + 256], acc1);
            }
            sta(xcatT + (256 + tid) * 32 + b, acc0);
            sta(xcatT + (512 + tid) * 32 + b, acc1);
        } else if (blk >= 64 && blk < 128) {
            // Whh_d x h_{t-1}: 64 blocks x 32 cols; h staged once into LDS
            int m = blk - 64;
            for (int i = tid; i < 16384; i += 256) xs[i] = lda(hdecT + i);
            __syncthreads();
            int b = tid & 31, cg = tid >> 5;        // cg 0..7
            int col0 = m * 32 + cg * 4;
            float acc[4] = {0.f, 0.f, 0.f, 0.f};
            const float* wp = WdT + (size_t)768 * 2048 + col0;
#pragma unroll 8
            for (int k = 0; k < 512; ++k) {
                float4 w = *(const float4*)(wp + (size_t)k * 2048);
                float xv = xs[k * 32 + b];
                acc[0] = fmaf(w.x, xv, acc[0]); acc[1] = fmaf(w.y, xv, acc[1]);
                acc[2] = fmaf(w.z, xv, acc[2]); acc[3] = fmaf(w.w, xv, acc[3]);
            }
#pragma unroll
            for (int j = 0; j < 4; ++j) sta(zp_h + (col0 + j) * 32 + b, acc[j]);
        }
        ++bgen; gbar(slots, gen, bgen, false);

        // ---------- phB: Wih x xcat + cell. blocks 0..127, 4 units each
        if (blk < 128) {
            int b = tid & 31, cg = (tid >> 5) & 3, kh = tid >> 7;
            int col0 = blk * 16 + cg * 4;
            float acc[4] = {0.f, 0.f, 0.f, 0.f};
            const float* wp = WdT + col0;
            for (int cc = 0; cc < 2; ++cc) {
                for (int i = tid; i < 12288; i += 256) xs[i] = lda(xcatT + cc * 12288 + i);
                __syncthreads();
                int kbeg = kh * 192;
#pragma unroll 4
                for (int kk = 0; kk < 192; ++kk) {
                    int k = kbeg + kk;
                    float4 w = *(const float4*)(wp + (size_t)(cc * 384 + k) * 2048);
                    float xv = xs[k * 32 + b];
                    acc[0] = fmaf(w.x, xv, acc[0]); acc[1] = fmaf(w.y, xv, acc[1]);
                    acc[2] = fmaf(w.z, xv, acc[2]); acc[3] = fmaf(w.w, xv, acc[3]);
                }
                __syncthreads();
            }
            float* zs = xs + S0;   // [kh2][cg4][g4][b32] = 1024
            zs[((kh * 4 + cg) * 4 + 0) * 32 + b] = acc[0];
            zs[((kh * 4 + cg) * 4 + 1) * 32 + b] = acc[1];
            zs[((kh * 4 + cg) * 4 + 2) * 32 + b] = acc[2];
            zs[((kh * 4 + cg) * 4 + 3) * 32 + b] = acc[3];
            __syncthreads();
            if (tid < 128) {
                int ul = tid >> 5, bb = tid & 31;
                int u = blk * 4 + ul;
                float z[4];
#pragma unroll
                for (int g = 0; g < 4; ++g)
                    z[g] = zs[((0 * 4 + ul) * 4 + g) * 32 + bb]
                         + zs[((1 * 4 + ul) * 4 + g) * 32 + bb]
                         + lda(zp_h + (u * 4 + g) * 32 + bb)
                         + bih_d[g * H2 + u] + bhh_d[g * H2 + u];
                float cp = cdecT[u * 32 + bb];
                float c2v = sigf(z[1]) * cp + sigf(z[0]) * ftanh(z[2]);
                cdecT[u * 32 + bb] = c2v;
                sta(hdecT + u * 32 + bb, sigf(z[3]) * ftanh(c2v));
            }
        }
        ++bgen; gbar(slots, gen, bgen, false);

        // ---------- phC: logits (0..499) + q piggyback (500..507)
        if (blk < 508) {
            for (int i = tid; i < 16384; i += 256)
                xs[(i >> 5) * 36 + (i & 31)] = lda(hdecT + i);
            __syncthreads();
            bool isQ = (blk >= 500);
            const float* wb = isQ ? (WahT + (blk - 500) * 64) : (WoutT + blk * 64);
            const int wst = isQ ? H2 : V;
            int rp2 = rp * 2;
            float a0[32], a1[32];
#pragma unroll
            for (int j = 0; j < 32; ++j) { a0[j] = 0.f; a1[j] = 0.f; }
#pragma unroll 4
            for (int kk = 0; kk < 64; ++kk) {
                int k = kc + 8 * kk;
                float2 w = *(const float2*)(wb + (size_t)k * wst + rp2);
                const float* xp = xs + k * 36;
#pragma unroll
                for (int q = 0; q < 8; ++q) {
                    float4 xv = *(const float4*)(xp + q * 4);
                    a0[q*4+0] = fmaf(w.x, xv.x, a0[q*4+0]); a1[q*4+0] = fmaf(w.y, xv.x, a1[q*4+0]);
                    a0[q*4+1] = fmaf(w.x, xv.y, a0[q*4+1]); a1[q*4+1] = fmaf(w.y, xv.y, a1[q*4+1]);
                    a0[q*4+2] = fmaf(w.x, xv.z, a0[q*4+2]); a1[q*4+2] = fmaf(w.y, xv.z, a1[q*4+2]);
                    a0[q*4+3] = fmaf(w.x, xv.w, a0[q*4+3]); a1[q*4+3] = fmaf(w.y, xv.w, a1[q*4+3]);
                }
            }
#pragma unroll
            for (int j = 0; j < 32; ++j) {
                a0[j] += __shfl_xor(a0[j], 8); a0[j] += __shfl_xor(a0[j], 16); a0[j] += __shfl_xor(a0[j], 32);
                a1[j] += __shfl_xor(a1[j], 8); a1[j] += __shfl_xor(a1[j], 16); a1[j] += __shfl_xor(a1[j], 32);
            }
            __syncthreads();   // xs reads done; safe to alias z into xs
            if (!isQ) {
                if (((tid >> 3) & 7) == 0) {
#pragma unroll
                    for (int j = 0; j < 32; ++j) {
                        xs[(rp2    ) * 37 + j] = a0[j];
                        xs[(rp2 + 1) * 37 + j] = a1[j];
                    }
                }
                __syncthreads();
                int row0 = blk * 64;
                {
                    int r = tid & 63, bo = tid >> 6;
                    float bv = bout[row0 + r];
#pragma unroll
                    for (int e = 0; e < 8; ++e) {
                        int b = bo * 8 + e;
                        __builtin_nontemporal_store(xs[r * 37 + b] + bv,
                            out + ((size_t)(b * T) + t) * V + row0 + r);
                    }
                }
                float* pm8 = xs + S0; float* ps8 = pm8 + 256; int* pi8 = (int*)(ps8 + 256);
                {
                    int g = tid >> 5, b = tid & 31;
                    float m = -INFINITY, s = 0.f; int mi = 0;
#pragma unroll
                    for (int i = 0; i < 8; ++i) {
                        int rr = g * 8 + i;
                        float v = xs[rr * 37 + b] + bout[row0 + rr];
                        if (v > m) { s *= __expf(m - v); m = v; mi = row0 + rr; }
                        s += __expf(v - m);
                    }
                    pm8[g * 32 + b] = m; ps8[g * 32 + b] = s; pi8[g * 32 + b] = mi;
                }
                __syncthreads();
                if (tid < 32) {
                    int b = tid;
                    float m = pm8[b], s = ps8[b]; int mi = pi8[b];
#pragma unroll
                    for (int g = 1; g < 8; ++g) {
                        float m2 = pm8[g * 32 + b], s2 = ps8[g * 32 + b]; int i2 = pi8[g * 32 + b];
                        if (m2 > m)      { s = s2 + s * __expf(m - m2); m = m2; mi = i2; }
                        else if (m > m2) { s = s + s2 * __expf(m2 - m); }
                        else             { s = s + s2; mi = (mi < i2) ? mi : i2; }
                    }
                    sta(Pm + b * 512 + blk, m);
                    sta(Ps + b * 512 + blk, s);
                    stai(Pi + b * 512 + blk, mi);
                }
            } else {
                if (((tid >> 3) & 7) == 0) {
                    int j0 = (blk - 500) * 64 + rp2;
#pragma unroll
                    for (int b = 0; b < 32; ++b) {
                        sta(q_buf + b * H2 + j0, a0[b]);
                        sta(q_buf + b * H2 + j0 + 1, a1[b]);
                    }
                }
            }
        }
        ++bgen; gbar(slots, gen, bgen, false);
    }

    // ---------- tail: lse for t = 127
    if (blk < 32) {
        int b = blk;
        float* rm = xs + S0; float* rs = rm + 256;
        float m = -INFINITY, s = 0.f;
        for (int i = tid; i < 512; i += 256) {
            if (i < 500) {
                float m2 = lda(Pm + b * 512 + i), s2 = lda(Ps + b * 512 + i);
                if (m2 > m)      { s = s2 + s * __expf(m - m2); m = m2; }
                else if (m > m2) { s = s + s2 * __expf(m2 - m); }
                else             { s = s + s2; }
            }
        }
        rm[tid] = m; rs[tid] = s;
        __syncthreads();
        for (int off = 128; off >= 1; off >>= 1) {
            if (tid < off) {
                float m1 = rm[tid], m2 = rm[tid + off];
                float s1 = rs[tid], s2 = rs[tid + off];
                float m_, s_;
                if (m2 > m1)      { m_ = m2; s_ = s2 + s1 * __expf(m1 - m2); }
                else if (m1 > m2) { m_ = m1; s_ = s1 + s2 * __expf(m2 - m1); }
                else              { m_ = m1; s_ = s1 + s2; }
                rm[tid] = m_; rs[tid] = s_;
            }
            __syncthreads();
        }
        if (tid == 0) lse[b * T + (T - 1)] = rm[0] + logf(rs[0]);
    }
}

extern "C" void kernel_launch(void* const* d_in, const int* in_sizes, int n_in,
                              void* d_out, int out_size, void* d_ws, size_t ws_size,
                              hipStream_t stream) {
    const int* x          = (const int*)d_in[0];
    const float* emb_enc  = (const float*)d_in[1];
    const float* Wih_f    = (const float*)d_in[2];
    const float* Whh_f    = (const float*)d_in[3];
    const float* bih_f    = (const float*)d_in[4];
    const float* bhh_f    = (const float*)d_in[5];
    const float* Wih_b    = (const float*)d_in[6];
    const float* Whh_b    = (const float*)d_in[7];
    const float* bih_b    = (const float*)d_in[8];
    const float* bhh_b    = (const float*)d_in[9];
    const float* emb_dec  = (const float*)d_in[10];
    const float* Wa_h     = (const float*)d_in[11];
    const float* Wa_e     = (const float*)d_in[12];
    const float* v_a      = (const float*)d_in[13];
    const float* b_a      = (const float*)d_in[14];
    const float* Wih_d    = (const float*)d_in[15];
    const float* Whh_d    = (const float*)d_in[16];
    const float* bih_d    = (const float*)d_in[17];
    const float* bhh_d    = (const float*)d_in[18];
    const float* Wout     = (const float*)d_in[19];
    const float* bout     = (const float*)d_in[20];
    float* out = (float*)d_out;

    float* ws = (float*)d_ws;
    size_t o = 0;
    float* enc_out = ws + o; o += (size_t)B * T * H2;     // 2,097,152
    float* proj_e  = ws + o; o += (size_t)B * T * H2;     // 2,097,152
    float* WoutT   = ws + o; o += (size_t)H2 * V;         // 16,384,000
    float* WdT     = ws + o; o += (size_t)1280 * 2048;    // 2,621,440
    float* WencT   = ws + o; o += (size_t)512 * 2048;     // 1,048,576
    float* WahT    = ws + o; o += (size_t)H2 * H2;        // 262,144
    float* zpenc   = ws + o; o += 2 * 2 * 2048 * 32;      // 262,144
    float* hdecT   = ws + o; o += 16384;
    float* cdecT   = ws + o; o += 16384;
    float* xcatT   = ws + o; o += 768 * 32;               // 24,576
    float* q_buf   = ws + o; o += 16384;
    float* zp_h    = ws + o; o += 2048 * 32;              // 65,536
    float* Pm      = ws + o; o += 32 * 512;
    float* Ps      = ws + o; o += 32 * 512;
    float* lse     = ws + o; o += 32 * 128;
    int*   Pi      = (int*)(ws + o); o += 32 * 512;
    int*   slots   = (int*)(ws + o); o += 512 * 32;       // 128B-padded arrival slots
    int*   gen     = (int*)(ws + o); o += 32;

    hipMemsetAsync(slots, 0, (512 * 32 + 32) * sizeof(int), stream);

    k_tr<<<dim3(1000, 16), 256, 0, stream>>>(Wout, WoutT, V, H2);
    k_tr<<<dim3(16, 16), 256, 0, stream>>>(Wa_h, WahT, H2, H2);
    k_prep_encw<<<4096, 256, 0, stream>>>(Wih_f, Whh_f, Wih_b, Whh_b, WencT);
    k_prep_decw<<<10240, 256, 0, stream>>>(Wih_d, Whh_d, WdT);

    k_seq<<<NBLK, NTHR, LDS_FLOATS * sizeof(float), stream>>>(
        x, emb_enc, emb_dec,
        bih_f, bhh_f, bih_b, bhh_b, bih_d, bhh_d,
        Wa_e, Wa_h, b_a, v_a, bout,
        WencT, WdT, WoutT, WahT,
        enc_out, proj_e, zpenc,
        hdecT, cdecT, xcatT, q_buf, zp_h,
        Pm, Ps, Pi, lse, out, slots, gen);

    k_norm<<<4096, 256, 0, stream>>>(out, lse);
}

// Round 7
// 35929.669 us; speedup vs baseline: 1.3984x; 1.3984x over previous
//
#include <hip/hip_runtime.h>

#define V 32000
#define D 256
#define H 256
#define T 128
#define B 32
#define SOS 126
#define H2 512

#define NBLK 512
#define NTHR 256
#define SCOPE __HIP_MEMORY_SCOPE_AGENT
#define LDS_FLOATS 17408   // 16384 x-slab + 1024 scratch = 69632 B (2 blocks/CU)
#define S0 16384           // scratch base (floats)

typedef float f32x4 __attribute__((ext_vector_type(4)));
typedef float f32x2 __attribute__((ext_vector_type(2)));

// wide agent-scope (coherence-point) ops: issue many, wait once
#define AGLOAD(d, p) asm volatile("global_load_dwordx4 %0, %1, off sc0 sc1" : "=v"(d) : "v"(p))
#define AGSTORE(p, d) asm volatile("global_store_dwordx4 %0, %1, off sc0 sc1" :: "v"(p), "v"(d) : "memory")
#define AGWAIT2(a,b) asm volatile("s_waitcnt vmcnt(0)" : "+v"(a),"+v"(b) :: "memory")
#define AGWAIT6(a,b,c,d,e,f) asm volatile("s_waitcnt vmcnt(0)" : "+v"(a),"+v"(b),"+v"(c),"+v"(d),"+v"(e),"+v"(f) :: "memory")
#define AGWAIT8(a,b,c,d,e,f,g,h) asm volatile("s_waitcnt vmcnt(0)" : "+v"(a),"+v"(b),"+v"(c),"+v"(d),"+v"(e),"+v"(f),"+v"(g),"+v"(h) :: "memory")

__device__ __forceinline__ float sigf(float x) { return 1.f / (1.f + __expf(-x)); }
__device__ __forceinline__ float ftanh(float x) {
    x = fminf(15.f, fmaxf(-15.f, x));
    float e = __expf(2.f * x);
    return (e - 1.f) / (e + 1.f);
}

__device__ __forceinline__ float lda(const float* p) {
    return __hip_atomic_load(p, __ATOMIC_RELAXED, SCOPE);
}
__device__ __forceinline__ void sta(float* p, float v) {
    __hip_atomic_store(p, v, __ATOMIC_RELAXED, SCOPE);
}
__device__ __forceinline__ int ldai(const int* p) {
    return __hip_atomic_load(p, __ATOMIC_RELAXED, SCOPE);
}
__device__ __forceinline__ void stai(int* p, int v) {
    __hip_atomic_store(p, v, __ATOMIC_RELAXED, SCOPE);
}

__device__ __forceinline__ void amerge(float& m, float& s, int& mi, float m2, float s2, int i2) {
    if (m2 > m)      { s = s2 + s * __expf(m - m2); m = m2; mi = i2; }
    else if (m > m2) { s = s + s2 * __expf(m2 - m); }
    else             { s = s + s2; mi = (mi < i2) ? mi : i2; }
}

// ---------------- store-based grid barrier, fence-free in steady state
__device__ __forceinline__ void gbar(int* __restrict__ slots, int* __restrict__ gen,
                                     int tgt, bool heavy) {
    __syncthreads();
    if (threadIdx.x == 0) {
        if (heavy) __builtin_amdgcn_fence(__ATOMIC_RELEASE, "agent");
        stai(slots + (size_t)blockIdx.x * 32, tgt);
    }
    if (blockIdx.x == 0) {
        int i0 = (int)threadIdx.x * 2;
        unsigned g1 = 0;
        while (ldai(slots + (size_t)i0 * 32) < tgt) {
            __builtin_amdgcn_s_sleep(1);
            if (++g1 > 100000000u) break;
        }
        g1 = 0;
        while (ldai(slots + (size_t)(i0 + 1) * 32) < tgt) {
            __builtin_amdgcn_s_sleep(1);
            if (++g1 > 100000000u) break;
        }
        asm volatile("" ::: "memory");
        __syncthreads();
        if (threadIdx.x == 0) stai(gen, tgt);
    } else {
        if (threadIdx.x == 0) {
            unsigned gd = 0;
            while (ldai(gen) < tgt) {
                __builtin_amdgcn_s_sleep(4);
                if (++gd > 100000000u) break;
            }
            asm volatile("" ::: "memory");
        }
    }
    if (heavy && threadIdx.x == 0) __builtin_amdgcn_fence(__ATOMIC_ACQUIRE, "agent");
    __syncthreads();
}

// ---------------- fp32 transpose (for WahT)
__global__ __launch_bounds__(256) void k_tr(const float* __restrict__ src,
                                            float* __restrict__ dst, int R, int C) {
    __shared__ float tle[32][33];
    int rb = blockIdx.x * 32, cb = blockIdx.y * 32;
    int lr = threadIdx.x & 31, lc = threadIdx.x >> 5;
#pragma unroll
    for (int i = 0; i < 32; i += 8) tle[lc + i][lr] = src[(size_t)(rb + lc + i) * C + cb + lr];
    __syncthreads();
#pragma unroll
    for (int i = 0; i < 32; i += 8) dst[(size_t)(cb + lc + i) * R + rb + lr] = tle[lr][lc + i];
}

// ---------------- bf16 transpose (Wout -> WoutB[k][row] ushort, RNE)
__global__ __launch_bounds__(256) void k_trb(const float* __restrict__ src,
                                             unsigned short* __restrict__ dst, int R, int C) {
    __shared__ float tle[32][33];
    int rb = blockIdx.x * 32, cb = blockIdx.y * 32;
    int lr = threadIdx.x & 31, lc = threadIdx.x >> 5;
#pragma unroll
    for (int i = 0; i < 32; i += 8) tle[lc + i][lr] = src[(size_t)(rb + lc + i) * C + cb + lr];
    __syncthreads();
#pragma unroll
    for (int i = 0; i < 32; i += 8) {
        unsigned u = __float_as_uint(tle[lr][lc + i]);
        unsigned r = (u + 0x7fffu + ((u >> 16) & 1u)) >> 16;
        dst[(size_t)(cb + lc + i) * R + rb + lr] = (unsigned short)r;
    }
}

// ---------------- WencT[k][dir*1024 + u*4+g]
__global__ __launch_bounds__(256) void k_prep_encw(
    const float* __restrict__ Wih_f, const float* __restrict__ Whh_f,
    const float* __restrict__ Wih_b, const float* __restrict__ Whh_b,
    float* __restrict__ WencT) {
    int idx = blockIdx.x * 256 + threadIdx.x;     // 512*2048
    int k = idx >> 11, col = idx & 2047;
    int dir = col >> 10, cu = col & 1023;
    int u = cu >> 2, g = cu & 3;
    const float* Wih = dir ? Wih_b : Wih_f;
    const float* Whh = dir ? Whh_b : Whh_f;
    float v = (k < 256) ? Wih[(g * H + u) * D + k] : Whh[(g * H + u) * H + (k - 256)];
    WencT[idx] = v;
}

// ---------------- WdT[k][u*4+g]
__global__ __launch_bounds__(256) void k_prep_decw(const float* __restrict__ Wih_d,
                                                   const float* __restrict__ Whh_d,
                                                   float* __restrict__ WdT) {
    int idx = blockIdx.x * 256 + threadIdx.x;     // 1280*2048
    int k = idx >> 11, col = idx & 2047;
    int u = col >> 2, g = col & 3;
    float v = (k < 768) ? Wih_d[(size_t)(g * H2 + u) * 768 + k]
                        : Whh_d[(size_t)(g * H2 + u) * H2 + (k - 768)];
    WdT[idx] = v;
}

// ---------------- final: out = logits - lse[b*T+t]
__global__ __launch_bounds__(256) void k_norm(float* __restrict__ out,
                                              const float* __restrict__ lse) {
    const int total4 = B * T * V / 4;
    int stride = gridDim.x * 256;
    for (int i4 = blockIdx.x * 256 + threadIdx.x; i4 < total4; i4 += stride) {
        int rowv = i4 / (V / 4);
        float l = lse[rowv];
        float4* p = (float4*)out + i4;
        float4 v = *p;
        v.x -= l; v.y -= l; v.z -= l; v.w -= l;
        *p = v;
    }
}

// ==================== THE PERSISTENT KERNEL ====================
__global__ __launch_bounds__(256, 2) void k_seq(
    const int* __restrict__ x, const float* __restrict__ emb_enc,
    const float* __restrict__ emb_dec,
    const float* __restrict__ bih_f, const float* __restrict__ bhh_f,
    const float* __restrict__ bih_b, const float* __restrict__ bhh_b,
    const float* __restrict__ bih_d, const float* __restrict__ bhh_d,
    const float* __restrict__ Wa_e, const float* __restrict__ Wa_h,
    const float* __restrict__ b_a, const float* __restrict__ v_a,
    const float* __restrict__ bout,
    const float* __restrict__ WencT, const float* __restrict__ WdT,
    const unsigned short* __restrict__ WoutB, const float* __restrict__ WahT,
    float* __restrict__ enc_out, float* __restrict__ proj_e,
    float* __restrict__ zpenc,
    float* __restrict__ hdecT, float* __restrict__ cdecT,
    float* __restrict__ xcatT, float* __restrict__ q_buf, float* __restrict__ zp_h,
    float* __restrict__ P4, float* __restrict__ lse, float* __restrict__ out,
    int* slots, int* gen) {
    extern __shared__ float xs[];
    const int blk = blockIdx.x, tid = threadIdx.x;
    const int kc = (tid >> 3) & 7;
    const int rp = (tid >> 6) * 8 + (tid & 7);   // 0..31 across block
    int bgen = 0;
    float c_priv[16];

    // ===================== ENCODER =====================
    for (int t = 0; t <= T; ++t) {
        if (blk < 128) {
            int rowgrp = blk >> 2, c = (blk >> 1) & 1, bh = blk & 1;
            int dir = rowgrp >> 4;
            // ---- stage x-slab [256][16] xor-swizzled
            if (c == 0) {
                if (t < T) {
                    for (int i = tid; i < 4096; i += 256) {
                        int bb = i >> 8, k = i & 255;
                        int tok = x[(bh * 16 + bb) * T + t];
                        xs[k * 16 + (((bb & 12) ^ ((k & 3) << 2)) | (bb & 3))] =
                            emb_enc[tok * 256 + k];
                    }
                }
            } else {
                if (t == 0) {
#pragma unroll
                    for (int j = 0; j < 16; ++j) {
                        xs[tid + j * 256] = 0.f;
                        c_priv[j] = 0.f;
                    }
                } else {
                    bool writer = (rowgrp & 15) == 0;
                    const float* zpp = zpenc + ((t - 1) & 1) * 131072;
#pragma unroll
                    for (int j = 0; j < 16; ++j) {
                        int i = tid + j * 256;
                        int u = i >> 4, bb = i & 15, bG = bh * 16 + bb;
                        int r = dir * 1024 + u * 4;
                        float z[4];
#pragma unroll
                        for (int g = 0; g < 4; ++g) {
                            float bias = (dir ? bih_b : bih_f)[g * 256 + u] +
                                         (dir ? bhh_b : bhh_f)[g * 256 + u];
                            z[g] = lda(zpp + (size_t)(r + g) * 32 + bG) +
                                   lda(zpp + (size_t)(2048 + r + g) * 32 + bG) + bias;
                        }
                        float cp = c_priv[j];
                        float c2 = sigf(z[1]) * cp + sigf(z[0]) * ftanh(z[2]);
                        float h2 = sigf(z[3]) * ftanh(c2);
                        c_priv[j] = c2;
                        xs[u * 16 + (((bb & 12) ^ ((u & 3) << 2)) | (bb & 3))] = h2;
                        if (writer) {
                            enc_out[(size_t)(bG * T + (t - 1)) * H2 + dir * 256 + u] = h2;
                            if (t == T) {
                                hdecT[(dir * 256 + u) * 32 + bG] = h2;
                                cdecT[(dir * 256 + u) * 32 + bG] = c2;
                            }
                        }
                    }
                }
            }
            __syncthreads();
            // ---- mm -> zpenc[t&1][c]
            if (t < T) {
                int r0 = rowgrp * 64 + rp * 2;
                float a0[16], a1[16];
#pragma unroll
                for (int j = 0; j < 16; ++j) { a0[j] = 0.f; a1[j] = 0.f; }
#pragma unroll 4
                for (int j = 0; j < 32; ++j) {
                    int kl = kc + 8 * j;
                    float2 w = *(const float2*)(WencT + (size_t)(c * 256 + kl) * 2048 + r0);
                    const float* xp = xs + kl * 16;
                    int sw = (kl & 3) << 2;
#pragma unroll
                    for (int q = 0; q < 4; ++q) {
                        f32x4 xv = *(const f32x4*)(xp + ((q * 4) ^ sw));
                        a0[q*4+0] = fmaf(w.x, xv.x, a0[q*4+0]); a1[q*4+0] = fmaf(w.y, xv.x, a1[q*4+0]);
                        a0[q*4+1] = fmaf(w.x, xv.y, a0[q*4+1]); a1[q*4+1] = fmaf(w.y, xv.y, a1[q*4+1]);
                        a0[q*4+2] = fmaf(w.x, xv.z, a0[q*4+2]); a1[q*4+2] = fmaf(w.y, xv.z, a1[q*4+2]);
                        a0[q*4+3] = fmaf(w.x, xv.w, a0[q*4+3]); a1[q*4+3] = fmaf(w.y, xv.w, a1[q*4+3]);
                    }
                }
#pragma unroll
                for (int j = 0; j < 16; ++j) {
                    a0[j] += __shfl_xor(a0[j], 8); a0[j] += __shfl_xor(a0[j], 16); a0[j] += __shfl_xor(a0[j], 32);
                    a1[j] += __shfl_xor(a1[j], 8); a1[j] += __shfl_xor(a1[j], 16); a1[j] += __shfl_xor(a1[j], 32);
                }
                if (((tid >> 3) & 7) == 0) {
                    float* zb = zpenc + (t & 1) * 131072 + (size_t)(c * 2048 + r0) * 32 + bh * 16;
                    f32x4 s0 = {a0[0],a0[1],a0[2],a0[3]}, s1 = {a0[4],a0[5],a0[6],a0[7]};
                    f32x4 s2 = {a0[8],a0[9],a0[10],a0[11]}, s3 = {a0[12],a0[13],a0[14],a0[15]};
                    AGSTORE(zb, s0); AGSTORE(zb + 4, s1); AGSTORE(zb + 8, s2); AGSTORE(zb + 12, s3);
                    f32x4 t0 = {a1[0],a1[1],a1[2],a1[3]}, t1 = {a1[4],a1[5],a1[6],a1[7]};
                    f32x4 t2 = {a1[8],a1[9],a1[10],a1[11]}, t3 = {a1[12],a1[13],a1[14],a1[15]};
                    AGSTORE(zb + 32, t0); AGSTORE(zb + 36, t1); AGSTORE(zb + 40, t2); AGSTORE(zb + 44, t3);
                }
            }
        }
        ++bgen; gbar(slots, gen, bgen, t == T);
    }

    // ===================== pre-decoder: proj_e + q0 =====================
    {
        if (blk < 256) {
            int r0 = blk * 16;
            for (int i = tid; i < 16 * 512; i += 256) {
                int r = i >> 9, k = i & 511;
                xs[r * 512 + k] = enc_out[(size_t)(r0 + r) * H2 + k];
            }
            __syncthreads();
            int j0 = tid * 2;
            float acc0[16], acc1[16];
#pragma unroll
            for (int r = 0; r < 16; ++r) { acc0[r] = 0.f; acc1[r] = 0.f; }
            const float* w0 = Wa_e + j0 * H2;
            const float* w1 = Wa_e + (j0 + 1) * H2;
            for (int k = 0; k < H2; k += 4) {
                float4 wa = *(const float4*)(w0 + k);
                float4 wb = *(const float4*)(w1 + k);
#pragma unroll
                for (int r = 0; r < 16; ++r) {
                    float4 xv = *(const float4*)(&xs[r * 512 + k]);
                    acc0[r] = fmaf(wa.x, xv.x, acc0[r]); acc0[r] = fmaf(wa.y, xv.y, acc0[r]);
                    acc0[r] = fmaf(wa.z, xv.z, acc0[r]); acc0[r] = fmaf(wa.w, xv.w, acc0[r]);
                    acc1[r] = fmaf(wb.x, xv.x, acc1[r]); acc1[r] = fmaf(wb.y, xv.y, acc1[r]);
                    acc1[r] = fmaf(wb.z, xv.z, acc1[r]); acc1[r] = fmaf(wb.w, xv.w, acc1[r]);
                }
            }
#pragma unroll
            for (int r = 0; r < 16; ++r) {
                float2 st; st.x = acc0[r]; st.y = acc1[r];
                *(float2*)(proj_e + (size_t)(r0 + r) * H2 + j0) = st;
            }
        } else if (blk < 320) {
            int gi = (blk - 256) * 256 + tid;
            int j = gi >> 5, b = gi & 31;
            float a0 = 0, a1 = 0, a2 = 0, a3 = 0;
            const float* wr = Wa_h + (size_t)j * H2;
            for (int k = 0; k < H2; k += 4) {
                float4 w = *(const float4*)(wr + k);
                a0 = fmaf(w.x, hdecT[(k    ) * 32 + b], a0);
                a1 = fmaf(w.y, hdecT[(k + 1) * 32 + b], a1);
                a2 = fmaf(w.z, hdecT[(k + 2) * 32 + b], a2);
                a3 = fmaf(w.w, hdecT[(k + 3) * 32 + b], a3);
            }
            q_buf[b * H2 + j] = (a0 + a1) + (a2 + a3);
        }
    }
    ++bgen; gbar(slots, gen, bgen, true);

    // ===================== DECODER =====================
    for (int t = 0; t < T; ++t) {
        // ---------- phA: attention chain (0..31) || Whh x h_{t-1} (32..95)
        if (blk < 32) {
            int b = blk;
            int tok = SOS;
            if (t > 0) {
                float* rm = xs + S0; float* rs = rm + 256; int* ri = (int*)(rs + 256);
                float m = -INFINITY, s = 0.f; int mi = 0x7fffffff;
                {
                    const float* p0 = P4 + ((size_t)b * 512 + tid) * 4;
                    bool has1 = (tid + 256) < 500;
                    const float* p1 = has1 ? (p0 + 1024) : p0;
                    f32x4 v0, v1;
                    AGLOAD(v0, p0); AGLOAD(v1, p1);
                    AGWAIT2(v0, v1);
                    amerge(m, s, mi, v0.x, v0.y, __float_as_int(v0.z));
                    if (has1) amerge(m, s, mi, v1.x, v1.y, __float_as_int(v1.z));
                }
                rm[tid] = m; rs[tid] = s; ri[tid] = mi;
                __syncthreads();
                for (int off = 128; off >= 1; off >>= 1) {
                    if (tid < off) {
                        float m1 = rm[tid], m2 = rm[tid + off];
                        float s1 = rs[tid], s2 = rs[tid + off];
                        int i1 = ri[tid], i2 = ri[tid + off];
                        float m_, s_; int i_;
                        if (m2 > m1)      { m_ = m2; s_ = s2 + s1 * __expf(m1 - m2); i_ = i2; }
                        else if (m1 > m2) { m_ = m1; s_ = s1 + s2 * __expf(m2 - m1); i_ = i1; }
                        else              { m_ = m1; s_ = s1 + s2; i_ = (i1 < i2) ? i1 : i2; }
                        rm[tid] = m_; rs[tid] = s_; ri[tid] = i_;
                    }
                    __syncthreads();
                }
                if (tid == 0) lse[b * T + (t - 1)] = rm[0] + logf(rs[0]);
                __syncthreads();
                tok = ri[0];
                __syncthreads();
            }
            // embedding -> xcatT rows [0,256)
            sta(xcatT + tid * 32 + b, emb_dec[tok * 256 + tid]);
            // energy -> es (LDS)
            float* es = xs + S0;
            {
                int l = tid & 63, wv = tid >> 6;
                const float* qp = q_buf + (size_t)b * H2 + l * 8;
                f32x4 q0, q1;
                AGLOAD(q0, qp); AGLOAD(q1, qp + 4);
                AGWAIT2(q0, q1);
                f32x4 ba0 = *(const f32x4*)(b_a + l * 8);
                f32x4 ba1 = *(const f32x4*)(b_a + l * 8 + 4);
                f32x4 va0 = *(const f32x4*)(v_a + l * 8);
                f32x4 va1 = *(const f32x4*)(v_a + l * 8 + 4);
                q0 += ba0; q1 += ba1;
                for (int tti = 0; tti < 32; ++tti) {
                    int tt = wv * 32 + tti;
                    const f32x4* pp = (const f32x4*)(proj_e + ((size_t)(b * T) + tt) * H2 + l * 8);
                    f32x4 p0 = __builtin_nontemporal_load(pp);
                    f32x4 p1 = __builtin_nontemporal_load(pp + 1);
                    float s = ftanh(p0.x + q0.x) * va0.x + ftanh(p0.y + q0.y) * va0.y
                            + ftanh(p0.z + q0.z) * va0.z + ftanh(p0.w + q0.w) * va0.w
                            + ftanh(p1.x + q1.x) * va1.x + ftanh(p1.y + q1.y) * va1.y
                            + ftanh(p1.z + q1.z) * va1.z + ftanh(p1.w + q1.w) * va1.w;
#pragma unroll
                    for (int off = 32; off >= 1; off >>= 1) s += __shfl_xor(s, off);
                    if (l == 0) es[tt] = s;
                }
            }
            __syncthreads();
            // softmax over T=128
            float* red = xs + S0 + 128; float* wsm = xs + S0 + 256;
            if (tid < 128) red[tid] = es[tid];
            __syncthreads();
            for (int off = 64; off >= 1; off >>= 1) {
                if (tid < off) red[tid] = fmaxf(red[tid], red[tid + off]);
                __syncthreads();
            }
            float M = red[0];
            __syncthreads();
            float ev = 0.f;
            if (tid < 128) { ev = __expf(es[tid] - M); red[tid] = ev; }
            __syncthreads();
            for (int off = 64; off >= 1; off >>= 1) {
                if (tid < off) red[tid] += red[tid + off];
                __syncthreads();
            }
            float S = red[0];
            __syncthreads();
            if (tid < 128) wsm[tid] = ev / S;
            __syncthreads();
            // ctx -> xcatT rows [256,768)
            float acc0 = 0.f, acc1 = 0.f;
            const float* eo = enc_out + (size_t)b * T * H2;
#pragma unroll 8
            for (int t2 = 0; t2 < T; ++t2) {
                float wv2 = wsm[t2];
                acc0 = fmaf(wv2, __builtin_nontemporal_load(eo + t2 * H2 + tid), acc0);
                acc1 = fmaf(wv2, __builtin_nontemporal_load(eo + t2 * H2 + tid + 256), acc1);
            }
            sta(xcatT + (256 + tid) * 32 + b, acc0);
            sta(xcatT + (512 + tid) * 32 + b, acc1);
        } else if (blk < 96) {
            // Whh_d x h: 64 blocks = 32 colgrp x 2 bh. stage h-half [512][16] swizzled
            int m = blk - 32;
            int cg = m >> 1, bh = m & 1;
            {
                f32x4 v[8];
#pragma unroll
                for (int j = 0; j < 8; ++j) {
                    int i = tid + j * 256;
                    int row = i >> 2, b4 = (i & 3) * 4;
                    AGLOAD(v[j], hdecT + row * 32 + bh * 16 + b4);
                }
                AGWAIT8(v[0], v[1], v[2], v[3], v[4], v[5], v[6], v[7]);
#pragma unroll
                for (int j = 0; j < 8; ++j) {
                    int i = tid + j * 256;
                    int row = i >> 2, b4 = (i & 3) * 4;
                    *(f32x4*)(xs + row * 16 + (b4 ^ ((row & 3) << 2))) = v[j];
                }
            }
            __syncthreads();
            int r0 = rp * 2;
            int col = cg * 64 + r0;
            float a0[16], a1[16];
#pragma unroll
            for (int j = 0; j < 16; ++j) { a0[j] = 0.f; a1[j] = 0.f; }
#pragma unroll 4
            for (int kk = 0; kk < 64; ++kk) {
                int k = kc + 8 * kk;
                f32x2 w = __builtin_nontemporal_load(
                    (const f32x2*)(WdT + (size_t)(768 + k) * 2048 + col));
                const float* xp = xs + k * 16;
                int sw = (k & 3) << 2;
#pragma unroll
                for (int q = 0; q < 4; ++q) {
                    f32x4 xv = *(const f32x4*)(xp + ((q * 4) ^ sw));
                    a0[q*4+0] = fmaf(w.x, xv.x, a0[q*4+0]); a1[q*4+0] = fmaf(w.y, xv.x, a1[q*4+0]);
                    a0[q*4+1] = fmaf(w.x, xv.y, a0[q*4+1]); a1[q*4+1] = fmaf(w.y, xv.y, a1[q*4+1]);
                    a0[q*4+2] = fmaf(w.x, xv.z, a0[q*4+2]); a1[q*4+2] = fmaf(w.y, xv.z, a1[q*4+2]);
                    a0[q*4+3] = fmaf(w.x, xv.w, a0[q*4+3]); a1[q*4+3] = fmaf(w.y, xv.w, a1[q*4+3]);
                }
            }
#pragma unroll
            for (int j = 0; j < 16; ++j) {
                a0[j] += __shfl_xor(a0[j], 8); a0[j] += __shfl_xor(a0[j], 16); a0[j] += __shfl_xor(a0[j], 32);
                a1[j] += __shfl_xor(a1[j], 8); a1[j] += __shfl_xor(a1[j], 16); a1[j] += __shfl_xor(a1[j], 32);
            }
            if (((tid >> 3) & 7) == 0) {
                float* zb = zp_h + (size_t)col * 32 + bh * 16;
                f32x4 s0 = {a0[0],a0[1],a0[2],a0[3]}, s1 = {a0[4],a0[5],a0[6],a0[7]};
                f32x4 s2 = {a0[8],a0[9],a0[10],a0[11]}, s3 = {a0[12],a0[13],a0[14],a0[15]};
                AGSTORE(zb, s0); AGSTORE(zb + 4, s1); AGSTORE(zb + 8, s2); AGSTORE(zb + 12, s3);
                f32x4 t0 = {a1[0],a1[1],a1[2],a1[3]}, t1 = {a1[4],a1[5],a1[6],a1[7]};
                f32x4 t2 = {a1[8],a1[9],a1[10],a1[11]}, t3 = {a1[12],a1[13],a1[14],a1[15]};
                AGSTORE(zb + 32, t0); AGSTORE(zb + 36, t1); AGSTORE(zb + 40, t2); AGSTORE(zb + 44, t3);
            }
        }
        ++bgen; gbar(slots, gen, bgen, false);

        // ---------- phB: Wih x xcat + fused cell. 64 blocks = 32 colgrp x 2 bh
        if (blk < 64) {
            int cg = blk >> 1, bh = blk & 1;
            {
#pragma unroll
                for (int hh = 0; hh < 2; ++hh) {
                    f32x4 v[6];
#pragma unroll
                    for (int j = 0; j < 6; ++j) {
                        int i = tid + (hh * 6 + j) * 256;
                        int row = i >> 2, b4 = (i & 3) * 4;
                        AGLOAD(v[j], xcatT + row * 32 + bh * 16 + b4);
                    }
                    AGWAIT6(v[0], v[1], v[2], v[3], v[4], v[5]);
#pragma unroll
                    for (int j = 0; j < 6; ++j) {
                        int i = tid + (hh * 6 + j) * 256;
                        int row = i >> 2, b4 = (i & 3) * 4;
                        *(f32x4*)(xs + row * 16 + (b4 ^ ((row & 3) << 2))) = v[j];
                    }
                }
            }
            __syncthreads();
            int r0 = rp * 2;
            int col = cg * 64 + r0;
            float a0[16], a1[16];
#pragma unroll
            for (int j = 0; j < 16; ++j) { a0[j] = 0.f; a1[j] = 0.f; }
#pragma unroll 4
            for (int kk = 0; kk < 96; ++kk) {
                int k = kc + 8 * kk;
                f32x2 w = __builtin_nontemporal_load(
                    (const f32x2*)(WdT + (size_t)k * 2048 + col));
                const float* xp = xs + k * 16;
                int sw = (k & 3) << 2;
#pragma unroll
                for (int q = 0; q < 4; ++q) {
                    f32x4 xv = *(const f32x4*)(xp + ((q * 4) ^ sw));
                    a0[q*4+0] = fmaf(w.x, xv.x, a0[q*4+0]); a1[q*4+0] = fmaf(w.y, xv.x, a1[q*4+0]);
                    a0[q*4+1] = fmaf(w.x, xv.y, a0[q*4+1]); a1[q*4+1] = fmaf(w.y, xv.y, a1[q*4+1]);
                    a0[q*4+2] = fmaf(w.x, xv.z, a0[q*4+2]); a1[q*4+2] = fmaf(w.y, xv.z, a1[q*4+2]);
                    a0[q*4+3] = fmaf(w.x, xv.w, a0[q*4+3]); a1[q*4+3] = fmaf(w.y, xv.w, a1[q*4+3]);
                }
            }
#pragma unroll
            for (int j = 0; j < 16; ++j) {
                a0[j] += __shfl_xor(a0[j], 8); a0[j] += __shfl_xor(a0[j], 16); a0[j] += __shfl_xor(a0[j], 32);
                a1[j] += __shfl_xor(a1[j], 8); a1[j] += __shfl_xor(a1[j], 16); a1[j] += __shfl_xor(a1[j], 32);
            }
            float* zs = xs + S0;   // [64 colLocal][16 b]
            if (((tid >> 3) & 7) == 0) {
#pragma unroll
                for (int j = 0; j < 16; ++j) {
                    zs[r0 * 16 + j] = a0[j];
                    zs[(r0 + 1) * 16 + j] = a1[j];
                }
            }
            __syncthreads();
            // fused LSTM cell: 16 units x 16 b per block
            {
                int ul = tid >> 4, bl = tid & 15;
                int u = cg * 16 + ul, bb = bh * 16 + bl;
                float z[4];
#pragma unroll
                for (int g = 0; g < 4; ++g)
                    z[g] = zs[(ul * 4 + g) * 16 + bl]
                         + lda(zp_h + (size_t)(u * 4 + g) * 32 + bb)
                         + bih_d[g * H2 + u] + bhh_d[g * H2 + u];
                float cp = cdecT[u * 32 + bb];     // block-private across steps
                float c2 = sigf(z[1]) * cp + sigf(z[0]) * ftanh(z[2]);
                cdecT[u * 32 + bb] = c2;
                sta(hdecT + u * 32 + bb, sigf(z[3]) * ftanh(c2));
            }
        }
        ++bgen; gbar(slots, gen, bgen, false);

        // ---------- phC: logits bf16 (0..499) + q piggyback fp32 (500..507)
        if (blk < 508) {
            // stage h [512][32] xor-swizzled, wide agent loads
#pragma unroll
            for (int hh = 0; hh < 2; ++hh) {
                f32x4 v[8];
#pragma unroll
                for (int j = 0; j < 8; ++j) {
                    int i4 = tid + (hh * 8 + j) * 256;
                    AGLOAD(v[j], hdecT + (size_t)i4 * 4);
                }
                AGWAIT8(v[0], v[1], v[2], v[3], v[4], v[5], v[6], v[7]);
#pragma unroll
                for (int j = 0; j < 8; ++j) {
                    int i4 = tid + (hh * 8 + j) * 256;
                    int k = i4 >> 3, b4 = (i4 & 7) * 4;
                    *(f32x4*)(xs + k * 32 + (b4 ^ ((k & 7) << 2))) = v[j];
                }
            }
            __syncthreads();
            bool isQ = (blk >= 500);
            int rp2 = rp * 2;
            float a0[32], a1[32];
#pragma unroll
            for (int j = 0; j < 32; ++j) { a0[j] = 0.f; a1[j] = 0.f; }
            int sw = kc << 2;
            if (!isQ) {
                const unsigned short* wb = WoutB + blk * 64 + rp2;
#pragma unroll 4
                for (int kk = 0; kk < 64; ++kk) {
                    int k = kc + 8 * kk;
                    unsigned uw = *(const unsigned*)(wb + (size_t)k * V);
                    float wx = __uint_as_float(uw << 16);
                    float wy = __uint_as_float(uw & 0xffff0000u);
                    const float* xp = xs + k * 32;
#pragma unroll
                    for (int q = 0; q < 8; ++q) {
                        f32x4 xv = *(const f32x4*)(xp + ((q * 4) ^ sw));
                        a0[q*4+0] = fmaf(wx, xv.x, a0[q*4+0]); a1[q*4+0] = fmaf(wy, xv.x, a1[q*4+0]);
                        a0[q*4+1] = fmaf(wx, xv.y, a0[q*4+1]); a1[q*4+1] = fmaf(wy, xv.y, a1[q*4+1]);
                        a0[q*4+2] = fmaf(wx, xv.z, a0[q*4+2]); a1[q*4+2] = fmaf(wy, xv.z, a1[q*4+2]);
                        a0[q*4+3] = fmaf(wx, xv.w, a0[q*4+3]); a1[q*4+3] = fmaf(wy, xv.w, a1[q*4+3]);
                    }
                }
            } else {
                const float* wb = WahT + (blk - 500) * 64 + rp2;
#pragma unroll 4
                for (int kk = 0; kk < 64; ++kk) {
                    int k = kc + 8 * kk;
                    float2 w = *(const float2*)(wb + (size_t)k * H2);
                    const float* xp = xs + k * 32;
#pragma unroll
                    for (int q = 0; q < 8; ++q) {
                        f32x4 xv = *(const f32x4*)(xp + ((q * 4) ^ sw));
                        a0[q*4+0] = fmaf(w.x, xv.x, a0[q*4+0]); a1[q*4+0] = fmaf(w.y, xv.x, a1[q*4+0]);
                        a0[q*4+1] = fmaf(w.x, xv.y, a0[q*4+1]); a1[q*4+1] = fmaf(w.y, xv.y, a1[q*4+1]);
                        a0[q*4+2] = fmaf(w.x, xv.z, a0[q*4+2]); a1[q*4+2] = fmaf(w.y, xv.z, a1[q*4+2]);
                        a0[q*4+3] = fmaf(w.x, xv.w, a0[q*4+3]); a1[q*4+3] = fmaf(w.y, xv.w, a1[q*4+3]);
                    }
                }
            }
#pragma unroll
            for (int j = 0; j < 32; ++j) {
                a0[j] += __shfl_xor(a0[j], 8); a0[j] += __shfl_xor(a0[j], 16); a0[j] += __shfl_xor(a0[j], 32);
                a1[j] += __shfl_xor(a1[j], 8); a1[j] += __shfl_xor(a1[j], 16); a1[j] += __shfl_xor(a1[j], 32);
            }
            __syncthreads();   // x-slab free; alias z into xs
            if (!isQ) {
                if (((tid >> 3) & 7) == 0) {
#pragma unroll
                    for (int j = 0; j < 32; ++j) {
                        xs[(rp2    ) * 37 + j] = a0[j];
                        xs[(rp2 + 1) * 37 + j] = a1[j];
                    }
                }
                __syncthreads();
                int row0 = blk * 64;
                {
                    int r = tid & 63, bo = tid >> 6;
                    float bv = bout[row0 + r];
#pragma unroll
                    for (int e = 0; e < 8; ++e) {
                        int b = bo * 8 + e;
                        __builtin_nontemporal_store(xs[r * 37 + b] + bv,
                            out + ((size_t)(b * T) + t) * V + row0 + r);
                    }
                }
                float* pm8 = xs + S0; float* ps8 = pm8 + 256; int* pi8 = (int*)(ps8 + 256);
                {
                    int g = tid >> 5, b = tid & 31;
                    float m = -INFINITY, s = 0.f; int mi = 0;
#pragma unroll
                    for (int i = 0; i < 8; ++i) {
                        int rr = g * 8 + i;
                        float v = xs[rr * 37 + b] + bout[row0 + rr];
                        if (v > m) { s *= __expf(m - v); m = v; mi = row0 + rr; }
                        s += __expf(v - m);
                    }
                    pm8[g * 32 + b] = m; ps8[g * 32 + b] = s; pi8[g * 32 + b] = mi;
                }
                __syncthreads();
                if (tid < 32) {
                    int b = tid;
                    float m = pm8[b], s = ps8[b]; int mi = pi8[b];
#pragma unroll
                    for (int g = 1; g < 8; ++g) {
                        float m2 = pm8[g * 32 + b], s2 = ps8[g * 32 + b]; int i2 = pi8[g * 32 + b];
                        amerge(m, s, mi, m2, s2, i2);
                    }
                    f32x4 pk; pk.x = m; pk.y = s; pk.z = __int_as_float(mi); pk.w = 0.f;
                    AGSTORE(P4 + ((size_t)b * 512 + blk) * 4, pk);
                }
            } else {
                if (((tid >> 3) & 7) == 0) {
                    int j0 = (blk - 500) * 64 + rp2;
#pragma unroll
                    for (int b = 0; b < 32; ++b) {
                        sta(q_buf + b * H2 + j0, a0[b]);
                        sta(q_buf + b * H2 + j0 + 1, a1[b]);
                    }
                }
            }
        }
        ++bgen; gbar(slots, gen, bgen, false);
    }

    // ---------- tail: lse for t = 127
    if (blk < 32) {
        int b = blk;
        float* rm = xs + S0; float* rs = rm + 256;
        float m = -INFINITY, s = 0.f; int mi = 0;
        {
            const float* p0 = P4 + ((size_t)b * 512 + tid) * 4;
            bool has1 = (tid + 256) < 500;
            const float* p1 = has1 ? (p0 + 1024) : p0;
            f32x4 v0, v1;
            AGLOAD(v0, p0); AGLOAD(v1, p1);
            AGWAIT2(v0, v1);
            amerge(m, s, mi, v0.x, v0.y, __float_as_int(v0.z));
            if (has1) amerge(m, s, mi, v1.x, v1.y, __float_as_int(v1.z));
        }
        rm[tid] = m; rs[tid] = s;
        __syncthreads();
        for (int off = 128; off >= 1; off >>= 1) {
            if (tid < off) {
                float m1 = rm[tid], m2 = rm[tid + off];
                float s1 = rs[tid], s2 = rs[tid + off];
                float m_, s_;
                if (m2 > m1)      { m_ = m2; s_ = s2 + s1 * __expf(m1 - m2); }
                else if (m1 > m2) { m_ = m1; s_ = s1 + s2 * __expf(m2 - m1); }
                else              { m_ = m1; s_ = s1 + s2; }
                rm[tid] = m_; rs[tid] = s_;
            }
            __syncthreads();
        }
        if (tid == 0) lse[b * T + (T - 1)] = rm[0] + logf(rs[0]);
    }
}

extern "C" void kernel_launch(void* const* d_in, const int* in_sizes, int n_in,
                              void* d_out, int out_size, void* d_ws, size_t ws_size,
                              hipStream_t stream) {
    const int* x          = (const int*)d_in[0];
    const float* emb_enc  = (const float*)d_in[1];
    const float* Wih_f    = (const float*)d_in[2];
    const float* Whh_f    = (const float*)d_in[3];
    const float* bih_f    = (const float*)d_in[4];
    const float* bhh_f    = (const float*)d_in[5];
    const float* Wih_b    = (const float*)d_in[6];
    const float* Whh_b    = (const float*)d_in[7];
    const float* bih_b    = (const float*)d_in[8];
    const float* bhh_b    = (const float*)d_in[9];
    const float* emb_dec  = (const float*)d_in[10];
    const float* Wa_h     = (const float*)d_in[11];
    const float* Wa_e     = (const float*)d_in[12];
    const float* v_a      = (const float*)d_in[13];
    const float* b_a      = (const float*)d_in[14];
    const float* Wih_d    = (const float*)d_in[15];
    const float* Whh_d    = (const float*)d_in[16];
    const float* bih_d    = (const float*)d_in[17];
    const float* bhh_d    = (const float*)d_in[18];
    const float* Wout     = (const float*)d_in[19];
    const float* bout     = (const float*)d_in[20];
    float* out = (float*)d_out;

    float* ws = (float*)d_ws;
    size_t o = 0;
    float* enc_out = ws + o; o += (size_t)B * T * H2;       // 2,097,152
    float* proj_e  = ws + o; o += (size_t)B * T * H2;       // 2,097,152
    unsigned short* WoutB = (unsigned short*)(ws + o); o += (size_t)H2 * V / 2;  // 8,192,000 floats
    float* WdT     = ws + o; o += (size_t)1280 * 2048;      // 2,621,440
    float* WencT   = ws + o; o += (size_t)512 * 2048;       // 1,048,576
    float* WahT    = ws + o; o += (size_t)H2 * H2;          // 262,144
    float* zpenc   = ws + o; o += 2 * 2 * 2048 * 32;        // 262,144
    float* hdecT   = ws + o; o += 16384;
    float* cdecT   = ws + o; o += 16384;
    float* xcatT   = ws + o; o += 768 * 32;                 // 24,576
    float* q_buf   = ws + o; o += 16384;
    float* zp_h    = ws + o; o += 2048 * 32;                // 65,536
    float* P4      = ws + o; o += (size_t)32 * 512 * 4;     // 65,536
    float* lse     = ws + o; o += 32 * 128;
    int*   slots   = (int*)(ws + o); o += 512 * 32;
    int*   gen     = (int*)(ws + o); o += 32;

    hipMemsetAsync(slots, 0, (512 * 32 + 32) * sizeof(int), stream);

    k_trb<<<dim3(1000, 16), 256, 0, stream>>>(Wout, WoutB, V, H2);
    k_tr<<<dim3(16, 16), 256, 0, stream>>>(Wa_h, WahT, H2, H2);
    k_prep_encw<<<4096, 256, 0, stream>>>(Wih_f, Whh_f, Wih_b, Whh_b, WencT);
    k_prep_decw<<<10240, 256, 0, stream>>>(Wih_d, Whh_d, WdT);

    k_seq<<<NBLK, NTHR, LDS_FLOATS * sizeof(float), stream>>>(
        x, emb_enc, emb_dec,
        bih_f, bhh_f, bih_b, bhh_b, bih_d, bhh_d,
        Wa_e, Wa_h, b_a, v_a, bout,
        WencT, WdT, WoutB, WahT,
        enc_out, proj_e, zpenc,
        hdecT, cdecT, xcatT, q_buf, zp_h,
        P4, lse, out, slots, gen);

    k_norm<<<4096, 256, 0, stream>>>(out, lse);
}

// Round 8
// 29987.726 us; speedup vs baseline: 1.6755x; 1.1981x over previous
//
#include <hip/hip_runtime.h>

#define V 32000
#define D 256
#define H 256
#define T 128
#define B 32
#define SOS 126
#define H2 512

#define NBLK 512
#define NTHR 256
#define SCOPE __HIP_MEMORY_SCOPE_AGENT
#define LDS_FLOATS 17408   // 16384 x-slab + 1024 scratch = 69632 B (2 blocks/CU)
#define S0 16384           // scratch base (floats)

typedef float f32x4 __attribute__((ext_vector_type(4)));

// wide agent-scope (L2-bypass, L3-coherent) ops for cross-block state only
#define AGLOAD(d, p) asm volatile("global_load_dwordx4 %0, %1, off sc0 sc1" : "=v"(d) : "v"(p))
#define AGSTORE(p, d) asm volatile("global_store_dwordx4 %0, %1, off sc0 sc1" :: "v"(p), "v"(d) : "memory")
#define AGWAIT2(a,b) asm volatile("s_waitcnt vmcnt(0)" : "+v"(a),"+v"(b) :: "memory")
#define AGWAIT6(a,b,c,d,e,f) asm volatile("s_waitcnt vmcnt(0)" : "+v"(a),"+v"(b),"+v"(c),"+v"(d),"+v"(e),"+v"(f) :: "memory")
#define AGWAIT6P(a,b,c,d,e,f) asm volatile("s_waitcnt vmcnt(6)" : "+v"(a),"+v"(b),"+v"(c),"+v"(d),"+v"(e),"+v"(f) :: "memory")
#define AGWAIT8(a,b,c,d,e,f,g,h) asm volatile("s_waitcnt vmcnt(0)" : "+v"(a),"+v"(b),"+v"(c),"+v"(d),"+v"(e),"+v"(f),"+v"(g),"+v"(h) :: "memory")
#define AGWAIT8P(a,b,c,d,e,f,g,h) asm volatile("s_waitcnt vmcnt(8)" : "+v"(a),"+v"(b),"+v"(c),"+v"(d),"+v"(e),"+v"(f),"+v"(g),"+v"(h) :: "memory")

__device__ __forceinline__ float sigf(float x) { return 1.f / (1.f + __expf(-x)); }
__device__ __forceinline__ float ftanh(float x) {
    x = fminf(15.f, fmaxf(-15.f, x));
    float e = __expf(2.f * x);
    return (e - 1.f) / (e + 1.f);
}

__device__ __forceinline__ float lda(const float* p) {
    return __hip_atomic_load(p, __ATOMIC_RELAXED, SCOPE);
}
__device__ __forceinline__ void sta(float* p, float v) {
    __hip_atomic_store(p, v, __ATOMIC_RELAXED, SCOPE);
}
__device__ __forceinline__ int ldai(const int* p) {
    return __hip_atomic_load(p, __ATOMIC_RELAXED, SCOPE);
}
__device__ __forceinline__ void stai(int* p, int v) {
    __hip_atomic_store(p, v, __ATOMIC_RELAXED, SCOPE);
}

__device__ __forceinline__ void amerge(float& m, float& s, int& mi, float m2, float s2, int i2) {
    if (m2 > m)      { s = s2 + s * __expf(m - m2); m = m2; mi = i2; }
    else if (m > m2) { s = s + s2 * __expf(m2 - m); }
    else             { s = s + s2; mi = (mi < i2) ? mi : i2; }
}

// ---------------- grid barrier v3: active-set sweep + per-XCD gen replicas
__device__ __forceinline__ void gbar(int* __restrict__ slots, int* __restrict__ gen,
                                     int tgt, bool heavy, int nactive) {
    __syncthreads();
    if (threadIdx.x == 0 && ((int)blockIdx.x < nactive || blockIdx.x == 0)) {
        if (heavy) __builtin_amdgcn_fence(__ATOMIC_RELEASE, "agent");
        stai(slots + (size_t)blockIdx.x * 32, tgt);
    }
    if (blockIdx.x == 0) {
        for (int i = threadIdx.x; i < nactive; i += NTHR) {
            unsigned g1 = 0;
            while (ldai(slots + (size_t)i * 32) < tgt) {
                __builtin_amdgcn_s_sleep(1);
                if (++g1 > 100000000u) break;   // safety: garbage > hang
            }
        }
        asm volatile("" ::: "memory");
        __syncthreads();
        if (threadIdx.x < 8) stai(gen + threadIdx.x * 32, tgt);
    } else {
        if (threadIdx.x == 0) {
            const int* g = gen + (blockIdx.x & 7) * 32;
            unsigned gd = 0;
            while (ldai(g) < tgt) {
                __builtin_amdgcn_s_sleep(8);
                if (++gd > 100000000u) break;
            }
            asm volatile("" ::: "memory");
        }
    }
    if (heavy && threadIdx.x == 0) __builtin_amdgcn_fence(__ATOMIC_ACQUIRE, "agent");
    __syncthreads();
}

// ---------------- fp32 transpose (for WahT)
__global__ __launch_bounds__(256) void k_tr(const float* __restrict__ src,
                                            float* __restrict__ dst, int R, int C) {
    __shared__ float tle[32][33];
    int rb = blockIdx.x * 32, cb = blockIdx.y * 32;
    int lr = threadIdx.x & 31, lc = threadIdx.x >> 5;
#pragma unroll
    for (int i = 0; i < 32; i += 8) tle[lc + i][lr] = src[(size_t)(rb + lc + i) * C + cb + lr];
    __syncthreads();
#pragma unroll
    for (int i = 0; i < 32; i += 8) dst[(size_t)(cb + lc + i) * R + rb + lr] = tle[lr][lc + i];
}

// ---------------- bf16 transpose (Wout -> WoutB[k][row] ushort, RNE)
__global__ __launch_bounds__(256) void k_trb(const float* __restrict__ src,
                                             unsigned short* __restrict__ dst, int R, int C) {
    __shared__ float tle[32][33];
    int rb = blockIdx.x * 32, cb = blockIdx.y * 32;
    int lr = threadIdx.x & 31, lc = threadIdx.x >> 5;
#pragma unroll
    for (int i = 0; i < 32; i += 8) tle[lc + i][lr] = src[(size_t)(rb + lc + i) * C + cb + lr];
    __syncthreads();
#pragma unroll
    for (int i = 0; i < 32; i += 8) {
        unsigned u = __float_as_uint(tle[lr][lc + i]);
        unsigned r = (u + 0x7fffu + ((u >> 16) & 1u)) >> 16;
        dst[(size_t)(cb + lc + i) * R + rb + lr] = (unsigned short)r;
    }
}

// ---------------- WencT[k][dir*1024 + u*4+g]
__global__ __launch_bounds__(256) void k_prep_encw(
    const float* __restrict__ Wih_f, const float* __restrict__ Whh_f,
    const float* __restrict__ Wih_b, const float* __restrict__ Whh_b,
    float* __restrict__ WencT) {
    int idx = blockIdx.x * 256 + threadIdx.x;     // 512*2048
    int k = idx >> 11, col = idx & 2047;
    int dir = col >> 10, cu = col & 1023;
    int u = cu >> 2, g = cu & 3;
    const float* Wih = dir ? Wih_b : Wih_f;
    const float* Whh = dir ? Whh_b : Whh_f;
    float v = (k < 256) ? Wih[(g * H + u) * D + k] : Whh[(g * H + u) * H + (k - 256)];
    WencT[idx] = v;
}

// ---------------- WdT[k][u*4+g]
__global__ __launch_bounds__(256) void k_prep_decw(const float* __restrict__ Wih_d,
                                                   const float* __restrict__ Whh_d,
                                                   float* __restrict__ WdT) {
    int idx = blockIdx.x * 256 + threadIdx.x;     // 1280*2048
    int k = idx >> 11, col = idx & 2047;
    int u = col >> 2, g = col & 3;
    float v = (k < 768) ? Wih_d[(size_t)(g * H2 + u) * 768 + k]
                        : Whh_d[(size_t)(g * H2 + u) * H2 + (k - 768)];
    WdT[idx] = v;
}

// ---------------- final: out = logits - lse[b*T+t]
__global__ __launch_bounds__(256) void k_norm(float* __restrict__ out,
                                              const float* __restrict__ lse) {
    const int total4 = B * T * V / 4;
    int stride = gridDim.x * 256;
    for (int i4 = blockIdx.x * 256 + threadIdx.x; i4 < total4; i4 += stride) {
        int rowv = i4 / (V / 4);
        float l = lse[rowv];
        float4* p = (float4*)out + i4;
        float4 v = *p;
        v.x -= l; v.y -= l; v.z -= l; v.w -= l;
        *p = v;
    }
}

// ==================== THE PERSISTENT KERNEL ====================
__global__ __launch_bounds__(256, 2) void k_seq(
    const int* __restrict__ x, const float* __restrict__ emb_enc,
    const float* __restrict__ emb_dec,
    const float* __restrict__ bih_f, const float* __restrict__ bhh_f,
    const float* __restrict__ bih_b, const float* __restrict__ bhh_b,
    const float* __restrict__ bih_d, const float* __restrict__ bhh_d,
    const float* __restrict__ Wa_e, const float* __restrict__ Wa_h,
    const float* __restrict__ b_a, const float* __restrict__ v_a,
    const float* __restrict__ bout,
    const float* __restrict__ WencT, const float* __restrict__ WdT,
    const unsigned short* __restrict__ WoutB, const float* __restrict__ WahT,
    float* __restrict__ enc_out, float* __restrict__ proj_e,
    float* __restrict__ zpenc,
    float* __restrict__ hdecT, float* __restrict__ cdecT,
    float* __restrict__ xcatB, float* __restrict__ q_buf, float* __restrict__ zp_h,
    float* __restrict__ P4, float* __restrict__ lse, float* __restrict__ out,
    int* slots, int* gen) {
    extern __shared__ float xs[];
    const int blk = blockIdx.x, tid = threadIdx.x;
    const int kc = (tid >> 3) & 7;
    const int rp = (tid >> 6) * 8 + (tid & 7);   // 0..31 across block
    int bgen = 0;
    float c_priv[16];

    // ===================== ENCODER =====================
    for (int t = 0; t <= T; ++t) {
        if (blk < 128) {
            int rowgrp = blk >> 2, c = (blk >> 1) & 1, bh = blk & 1;
            int dir = rowgrp >> 4;
            // ---- stage x-slab [256][16] xor-swizzled
            if (c == 0) {
                if (t < T) {
                    for (int i = tid; i < 4096; i += 256) {
                        int bb = i >> 8, k = i & 255;
                        int tok = x[(bh * 16 + bb) * T + t];
                        xs[k * 16 + (((bb & 12) ^ ((k & 3) << 2)) | (bb & 3))] =
                            emb_enc[tok * 256 + k];
                    }
                }
            } else {
                if (t == 0) {
#pragma unroll
                    for (int j = 0; j < 16; ++j) {
                        xs[tid + j * 256] = 0.f;
                        c_priv[j] = 0.f;
                    }
                } else {
                    bool writer = (rowgrp & 15) == 0;
                    const float* zpp = zpenc + ((t - 1) & 1) * 131072;
#pragma unroll
                    for (int j = 0; j < 16; ++j) {
                        int i = tid + j * 256;
                        int u = i >> 4, bb = i & 15, bG = bh * 16 + bb;
                        int r = dir * 1024 + u * 4;
                        float z[4];
#pragma unroll
                        for (int g = 0; g < 4; ++g) {
                            float bias = (dir ? bih_b : bih_f)[g * 256 + u] +
                                         (dir ? bhh_b : bhh_f)[g * 256 + u];
                            z[g] = lda(zpp + (size_t)(r + g) * 32 + bG) +
                                   lda(zpp + (size_t)(2048 + r + g) * 32 + bG) + bias;
                        }
                        float cp = c_priv[j];
                        float c2 = sigf(z[1]) * cp + sigf(z[0]) * ftanh(z[2]);
                        float h2 = sigf(z[3]) * ftanh(c2);
                        c_priv[j] = c2;
                        xs[u * 16 + (((bb & 12) ^ ((u & 3) << 2)) | (bb & 3))] = h2;
                        if (writer) {
                            enc_out[(size_t)(bG * T + (t - 1)) * H2 + dir * 256 + u] = h2;
                            if (t == T) {
                                hdecT[(dir * 256 + u) * 32 + bG] = h2;
                                cdecT[(dir * 256 + u) * 32 + bG] = c2;
                            }
                        }
                    }
                }
            }
            __syncthreads();
            // ---- mm -> zpenc[t&1][c]
            if (t < T) {
                int r0 = rowgrp * 64 + rp * 2;
                float a0[16], a1[16];
#pragma unroll
                for (int j = 0; j < 16; ++j) { a0[j] = 0.f; a1[j] = 0.f; }
#pragma unroll 4
                for (int j = 0; j < 32; ++j) {
                    int kl = kc + 8 * j;
                    float2 w = *(const float2*)(WencT + (size_t)(c * 256 + kl) * 2048 + r0);
                    const float* xp = xs + kl * 16;
                    int sw = (kl & 3) << 2;
#pragma unroll
                    for (int q = 0; q < 4; ++q) {
                        f32x4 xv = *(const f32x4*)(xp + ((q * 4) ^ sw));
                        a0[q*4+0] = fmaf(w.x, xv.x, a0[q*4+0]); a1[q*4+0] = fmaf(w.y, xv.x, a1[q*4+0]);
                        a0[q*4+1] = fmaf(w.x, xv.y, a0[q*4+1]); a1[q*4+1] = fmaf(w.y, xv.y, a1[q*4+1]);
                        a0[q*4+2] = fmaf(w.x, xv.z, a0[q*4+2]); a1[q*4+2] = fmaf(w.y, xv.z, a1[q*4+2]);
                        a0[q*4+3] = fmaf(w.x, xv.w, a0[q*4+3]); a1[q*4+3] = fmaf(w.y, xv.w, a1[q*4+3]);
                    }
                }
#pragma unroll
                for (int j = 0; j < 16; ++j) {
                    a0[j] += __shfl_xor(a0[j], 8); a0[j] += __shfl_xor(a0[j], 16); a0[j] += __shfl_xor(a0[j], 32);
                    a1[j] += __shfl_xor(a1[j], 8); a1[j] += __shfl_xor(a1[j], 16); a1[j] += __shfl_xor(a1[j], 32);
                }
                if (((tid >> 3) & 7) == 0) {
                    float* zb = zpenc + (t & 1) * 131072 + (size_t)(c * 2048 + r0) * 32 + bh * 16;
                    f32x4 s0 = {a0[0],a0[1],a0[2],a0[3]}, s1 = {a0[4],a0[5],a0[6],a0[7]};
                    f32x4 s2 = {a0[8],a0[9],a0[10],a0[11]}, s3 = {a0[12],a0[13],a0[14],a0[15]};
                    AGSTORE(zb, s0); AGSTORE(zb + 4, s1); AGSTORE(zb + 8, s2); AGSTORE(zb + 12, s3);
                    f32x4 t0 = {a1[0],a1[1],a1[2],a1[3]}, t1 = {a1[4],a1[5],a1[6],a1[7]};
                    f32x4 t2 = {a1[8],a1[9],a1[10],a1[11]}, t3 = {a1[12],a1[13],a1[14],a1[15]};
                    AGSTORE(zb + 32, t0); AGSTORE(zb + 36, t1); AGSTORE(zb + 40, t2); AGSTORE(zb + 44, t3);
                }
            }
        }
        ++bgen; gbar(slots, gen, bgen, t == T, 128);
    }

    // ===================== pre-decoder: proj_e + q0 (normal ld/st) =====================
    {
        if (blk < 256) {
            int r0 = blk * 16;
            for (int i = tid; i < 16 * 512; i += 256) {
                int r = i >> 9, k = i & 511;
                xs[r * 512 + k] = enc_out[(size_t)(r0 + r) * H2 + k];
            }
            __syncthreads();
            int j0 = tid * 2;
            float acc0[16], acc1[16];
#pragma unroll
            for (int r = 0; r < 16; ++r) { acc0[r] = 0.f; acc1[r] = 0.f; }
            const float* w0 = Wa_e + j0 * H2;
            const float* w1 = Wa_e + (j0 + 1) * H2;
            for (int k = 0; k < H2; k += 4) {
                float4 wa = *(const float4*)(w0 + k);
                float4 wb = *(const float4*)(w1 + k);
#pragma unroll
                for (int r = 0; r < 16; ++r) {
                    float4 xv = *(const float4*)(&xs[r * 512 + k]);
                    acc0[r] = fmaf(wa.x, xv.x, acc0[r]); acc0[r] = fmaf(wa.y, xv.y, acc0[r]);
                    acc0[r] = fmaf(wa.z, xv.z, acc0[r]); acc0[r] = fmaf(wa.w, xv.w, acc0[r]);
                    acc1[r] = fmaf(wb.x, xv.x, acc1[r]); acc1[r] = fmaf(wb.y, xv.y, acc1[r]);
                    acc1[r] = fmaf(wb.z, xv.z, acc1[r]); acc1[r] = fmaf(wb.w, xv.w, acc1[r]);
                }
            }
#pragma unroll
            for (int r = 0; r < 16; ++r) {
                float2 st; st.x = acc0[r]; st.y = acc1[r];
                *(float2*)(proj_e + (size_t)(r0 + r) * H2 + j0) = st;
            }
        } else if (blk < 320) {
            int gi = (blk - 256) * 256 + tid;
            int j = gi >> 5, b = gi & 31;
            float a0 = 0, a1 = 0, a2 = 0, a3 = 0;
            const float* wr = Wa_h + (size_t)j * H2;
            for (int k = 0; k < H2; k += 4) {
                float4 w = *(const float4*)(wr + k);
                a0 = fmaf(w.x, hdecT[(k    ) * 32 + b], a0);
                a1 = fmaf(w.y, hdecT[(k + 1) * 32 + b], a1);
                a2 = fmaf(w.z, hdecT[(k + 2) * 32 + b], a2);
                a3 = fmaf(w.w, hdecT[(k + 3) * 32 + b], a3);
            }
            q_buf[b * H2 + j] = (a0 + a1) + (a2 + a3);
        }
    }
    ++bgen; gbar(slots, gen, bgen, true, 320);

    // ===================== DECODER =====================
    for (int t = 0; t < T; ++t) {
        // ---------- phA: attention chain (0..31) || Whh x h_{t-1} (32..95)
        if (blk < 32) {
            int b = blk;
            int tok = SOS;
            if (t > 0) {
                float* rm = xs + S0; float* rs = rm + 256; int* ri = (int*)(rs + 256);
                float m = -INFINITY, s = 0.f; int mi = 0x7fffffff;
                {
                    const float* p0 = P4 + ((size_t)b * 512 + tid) * 4;
                    bool has1 = (tid + 256) < 500;
                    const float* p1 = has1 ? (p0 + 1024) : p0;
                    f32x4 v0, v1;
                    AGLOAD(v0, p0); AGLOAD(v1, p1);
                    AGWAIT2(v0, v1);
                    amerge(m, s, mi, v0.x, v0.y, __float_as_int(v0.z));
                    if (has1) amerge(m, s, mi, v1.x, v1.y, __float_as_int(v1.z));
                }
                rm[tid] = m; rs[tid] = s; ri[tid] = mi;
                __syncthreads();
                for (int off = 128; off >= 1; off >>= 1) {
                    if (tid < off) {
                        float m1 = rm[tid], m2 = rm[tid + off];
                        float s1 = rs[tid], s2 = rs[tid + off];
                        int i1 = ri[tid], i2 = ri[tid + off];
                        float m_, s_; int i_;
                        if (m2 > m1)      { m_ = m2; s_ = s2 + s1 * __expf(m1 - m2); i_ = i2; }
                        else if (m1 > m2) { m_ = m1; s_ = s1 + s2 * __expf(m2 - m1); i_ = i1; }
                        else              { m_ = m1; s_ = s1 + s2; i_ = (i1 < i2) ? i1 : i2; }
                        rm[tid] = m_; rs[tid] = s_; ri[tid] = i_;
                    }
                    __syncthreads();
                }
                if (tid == 0) lse[b * T + (t - 1)] = rm[0] + logf(rs[0]);
                __syncthreads();
                tok = ri[0];
                __syncthreads();
            }
            // embedding -> xcatB[b][0:256) (coalesced row)
            sta(xcatB + (size_t)b * 768 + tid, emb_dec[tok * 256 + tid]);
            // energy -> es (LDS); cached proj_e loads (L2-resident slice)
            float* es = xs + S0;
            {
                int l = tid & 63, wv = tid >> 6;
                const float* qp = q_buf + (size_t)b * H2 + l * 8;
                f32x4 q0, q1;
                AGLOAD(q0, qp); AGLOAD(q1, qp + 4);
                AGWAIT2(q0, q1);
                f32x4 ba0 = *(const f32x4*)(b_a + l * 8);
                f32x4 ba1 = *(const f32x4*)(b_a + l * 8 + 4);
                f32x4 va0 = *(const f32x4*)(v_a + l * 8);
                f32x4 va1 = *(const f32x4*)(v_a + l * 8 + 4);
                q0 += ba0; q1 += ba1;
#pragma unroll 4
                for (int tti = 0; tti < 32; ++tti) {
                    int tt = wv * 32 + tti;
                    const float* pp = proj_e + ((size_t)(b * T) + tt) * H2 + l * 8;
                    f32x4 p0 = *(const f32x4*)(pp);
                    f32x4 p1 = *(const f32x4*)(pp + 4);
                    float s = ftanh(p0.x + q0.x) * va0.x + ftanh(p0.y + q0.y) * va0.y
                            + ftanh(p0.z + q0.z) * va0.z + ftanh(p0.w + q0.w) * va0.w
                            + ftanh(p1.x + q1.x) * va1.x + ftanh(p1.y + q1.y) * va1.y
                            + ftanh(p1.z + q1.z) * va1.z + ftanh(p1.w + q1.w) * va1.w;
#pragma unroll
                    for (int off = 32; off >= 1; off >>= 1) s += __shfl_xor(s, off);
                    if (l == 0) es[tt] = s;
                }
            }
            __syncthreads();
            // softmax over T=128
            float* red = xs + S0 + 128; float* wsm = xs + S0 + 256;
            if (tid < 128) red[tid] = es[tid];
            __syncthreads();
            for (int off = 64; off >= 1; off >>= 1) {
                if (tid < off) red[tid] = fmaxf(red[tid], red[tid + off]);
                __syncthreads();
            }
            float M = red[0];
            __syncthreads();
            float ev = 0.f;
            if (tid < 128) { ev = __expf(es[tid] - M); red[tid] = ev; }
            __syncthreads();
            for (int off = 64; off >= 1; off >>= 1) {
                if (tid < off) red[tid] += red[tid + off];
                __syncthreads();
            }
            float S = red[0];
            __syncthreads();
            if (tid < 128) wsm[tid] = ev / S;
            __syncthreads();
            // ctx -> xcatB[b][256:768) ; cached enc_out loads
            float acc0 = 0.f, acc1 = 0.f;
            const float* eo = enc_out + (size_t)b * T * H2;
#pragma unroll 8
            for (int t2 = 0; t2 < T; ++t2) {
                float wv2 = wsm[t2];
                acc0 = fmaf(wv2, eo[t2 * H2 + tid], acc0);
                acc1 = fmaf(wv2, eo[t2 * H2 + tid + 256], acc1);
            }
            sta(xcatB + (size_t)b * 768 + 256 + tid, acc0);
            sta(xcatB + (size_t)b * 768 + 512 + tid, acc1);
        } else if (blk < 96) {
            // Whh_d x h: 64 blocks = 32 colgrp x 2 bh. stage h-half [512][16] swizzled
            int m = blk - 32;
            int cg = m >> 1, bh = m & 1;
            {
                f32x4 v[8];
#pragma unroll
                for (int j = 0; j < 8; ++j) {
                    int i = tid + j * 256;
                    int row = i >> 2, b4 = (i & 3) * 4;
                    AGLOAD(v[j], hdecT + row * 32 + bh * 16 + b4);
                }
                AGWAIT8(v[0], v[1], v[2], v[3], v[4], v[5], v[6], v[7]);
#pragma unroll
                for (int j = 0; j < 8; ++j) {
                    int i = tid + j * 256;
                    int row = i >> 2, b4 = (i & 3) * 4;
                    *(f32x4*)(xs + row * 16 + (b4 ^ ((row & 3) << 2))) = v[j];
                }
            }
            __syncthreads();
            int r0 = rp * 2;
            int col = cg * 64 + r0;
            float a0[16], a1[16];
#pragma unroll
            for (int j = 0; j < 16; ++j) { a0[j] = 0.f; a1[j] = 0.f; }
#pragma unroll 4
            for (int kk = 0; kk < 64; ++kk) {
                int k = kc + 8 * kk;
                float2 w = *(const float2*)(WdT + (size_t)(768 + k) * 2048 + col);
                const float* xp = xs + k * 16;
                int sw = (k & 3) << 2;
#pragma unroll
                for (int q = 0; q < 4; ++q) {
                    f32x4 xv = *(const f32x4*)(xp + ((q * 4) ^ sw));
                    a0[q*4+0] = fmaf(w.x, xv.x, a0[q*4+0]); a1[q*4+0] = fmaf(w.y, xv.x, a1[q*4+0]);
                    a0[q*4+1] = fmaf(w.x, xv.y, a0[q*4+1]); a1[q*4+1] = fmaf(w.y, xv.y, a1[q*4+1]);
                    a0[q*4+2] = fmaf(w.x, xv.z, a0[q*4+2]); a1[q*4+2] = fmaf(w.y, xv.z, a1[q*4+2]);
                    a0[q*4+3] = fmaf(w.x, xv.w, a0[q*4+3]); a1[q*4+3] = fmaf(w.y, xv.w, a1[q*4+3]);
                }
            }
#pragma unroll
            for (int j = 0; j < 16; ++j) {
                a0[j] += __shfl_xor(a0[j], 8); a0[j] += __shfl_xor(a0[j], 16); a0[j] += __shfl_xor(a0[j], 32);
                a1[j] += __shfl_xor(a1[j], 8); a1[j] += __shfl_xor(a1[j], 16); a1[j] += __shfl_xor(a1[j], 32);
            }
            if (((tid >> 3) & 7) == 0) {
                float* zb = zp_h + (size_t)col * 32 + bh * 16;
                f32x4 s0 = {a0[0],a0[1],a0[2],a0[3]}, s1 = {a0[4],a0[5],a0[6],a0[7]};
                f32x4 s2 = {a0[8],a0[9],a0[10],a0[11]}, s3 = {a0[12],a0[13],a0[14],a0[15]};
                AGSTORE(zb, s0); AGSTORE(zb + 4, s1); AGSTORE(zb + 8, s2); AGSTORE(zb + 12, s3);
                f32x4 t0 = {a1[0],a1[1],a1[2],a1[3]}, t1 = {a1[4],a1[5],a1[6],a1[7]};
                f32x4 t2 = {a1[8],a1[9],a1[10],a1[11]}, t3 = {a1[12],a1[13],a1[14],a1[15]};
                AGSTORE(zb + 32, t0); AGSTORE(zb + 36, t1); AGSTORE(zb + 40, t2); AGSTORE(zb + 44, t3);
            }
        }
        ++bgen; gbar(slots, gen, bgen, false, 96);

        // ---------- phB: Wih x xcat + fused cell. 64 blocks = 32 colgrp x 2 bh
        if (blk < 64) {
            int cg = blk >> 1, bh = blk & 1;
            {
                // stage 16 b-rows x 768 k from xcatB[b][768] -> xs[k][16] swizzled
                int bb = tid & 15, ch = tid >> 4;   // ch 0..15
                const float* src = xcatB + (size_t)(bh * 16 + bb) * 768 + ch * 48;
                f32x4 v[12];
#pragma unroll
                for (int j = 0; j < 12; ++j) AGLOAD(v[j], src + j * 4);
                AGWAIT6P(v[0], v[1], v[2], v[3], v[4], v[5]);
#pragma unroll
                for (int j = 0; j < 6; ++j) {
#pragma unroll
                    for (int e = 0; e < 4; ++e) {
                        int k = ch * 48 + j * 4 + e;
                        xs[k * 16 + (((bb & 12) ^ ((k & 3) << 2)) | (bb & 3))] = v[j][e];
                    }
                }
                AGWAIT6(v[6], v[7], v[8], v[9], v[10], v[11]);
#pragma unroll
                for (int j = 6; j < 12; ++j) {
#pragma unroll
                    for (int e = 0; e < 4; ++e) {
                        int k = ch * 48 + j * 4 + e;
                        xs[k * 16 + (((bb & 12) ^ ((k & 3) << 2)) | (bb & 3))] = v[j][e];
                    }
                }
            }
            __syncthreads();
            int r0 = rp * 2;
            int col = cg * 64 + r0;
            float a0[16], a1[16];
#pragma unroll
            for (int j = 0; j < 16; ++j) { a0[j] = 0.f; a1[j] = 0.f; }
#pragma unroll 4
            for (int kk = 0; kk < 96; ++kk) {
                int k = kc + 8 * kk;
                float2 w = *(const float2*)(WdT + (size_t)k * 2048 + col);
                const float* xp = xs + k * 16;
                int sw = (k & 3) << 2;
#pragma unroll
                for (int q = 0; q < 4; ++q) {
                    f32x4 xv = *(const f32x4*)(xp + ((q * 4) ^ sw));
                    a0[q*4+0] = fmaf(w.x, xv.x, a0[q*4+0]); a1[q*4+0] = fmaf(w.y, xv.x, a1[q*4+0]);
                    a0[q*4+1] = fmaf(w.x, xv.y, a0[q*4+1]); a1[q*4+1] = fmaf(w.y, xv.y, a1[q*4+1]);
                    a0[q*4+2] = fmaf(w.x, xv.z, a0[q*4+2]); a1[q*4+2] = fmaf(w.y, xv.z, a1[q*4+2]);
                    a0[q*4+3] = fmaf(w.x, xv.w, a0[q*4+3]); a1[q*4+3] = fmaf(w.y, xv.w, a1[q*4+3]);
                }
            }
#pragma unroll
            for (int j = 0; j < 16; ++j) {
                a0[j] += __shfl_xor(a0[j], 8); a0[j] += __shfl_xor(a0[j], 16); a0[j] += __shfl_xor(a0[j], 32);
                a1[j] += __shfl_xor(a1[j], 8); a1[j] += __shfl_xor(a1[j], 16); a1[j] += __shfl_xor(a1[j], 32);
            }
            float* zs = xs + S0;   // [64 colLocal][16 b]
            if (((tid >> 3) & 7) == 0) {
#pragma unroll
                for (int j = 0; j < 16; ++j) {
                    zs[r0 * 16 + j] = a0[j];
                    zs[(r0 + 1) * 16 + j] = a1[j];
                }
            }
            __syncthreads();
            // fused LSTM cell: 16 units x 16 b per block
            {
                int ul = tid >> 4, bl = tid & 15;
                int u = cg * 16 + ul, bb = bh * 16 + bl;
                float z[4];
#pragma unroll
                for (int g = 0; g < 4; ++g)
                    z[g] = zs[(ul * 4 + g) * 16 + bl]
                         + lda(zp_h + (size_t)(u * 4 + g) * 32 + bb)
                         + bih_d[g * H2 + u] + bhh_d[g * H2 + u];
                float cp = cdecT[u * 32 + bb];     // block-private across steps
                float c2 = sigf(z[1]) * cp + sigf(z[0]) * ftanh(z[2]);
                cdecT[u * 32 + bb] = c2;
                sta(hdecT + u * 32 + bb, sigf(z[3]) * ftanh(c2));
            }
        }
        ++bgen; gbar(slots, gen, bgen, false, 64);

        // ---------- phC: logits bf16 (0..499) + q piggyback fp32 (500..507)
        if (blk < 508) {
            // stage h [512][32] xor-swizzled; 16 wide sc1 loads, pipelined wait
            {
                f32x4 v[16];
#pragma unroll
                for (int j = 0; j < 16; ++j)
                    AGLOAD(v[j], hdecT + (size_t)(tid + j * 256) * 4);
                AGWAIT8P(v[0], v[1], v[2], v[3], v[4], v[5], v[6], v[7]);
#pragma unroll
                for (int j = 0; j < 8; ++j) {
                    int i4 = tid + j * 256;
                    int k = i4 >> 3, b4 = (i4 & 7) * 4;
                    *(f32x4*)(xs + k * 32 + (b4 ^ ((k & 7) << 2))) = v[j];
                }
                AGWAIT8(v[8], v[9], v[10], v[11], v[12], v[13], v[14], v[15]);
#pragma unroll
                for (int j = 8; j < 16; ++j) {
                    int i4 = tid + j * 256;
                    int k = i4 >> 3, b4 = (i4 & 7) * 4;
                    *(f32x4*)(xs + k * 32 + (b4 ^ ((k & 7) << 2))) = v[j];
                }
            }
            __syncthreads();
            bool isQ = (blk >= 500);
            int rp2 = rp * 2;
            float a0[32], a1[32];
#pragma unroll
            for (int j = 0; j < 32; ++j) { a0[j] = 0.f; a1[j] = 0.f; }
            int sw = kc << 2;
            if (!isQ) {
                const unsigned short* wb = WoutB + blk * 64 + rp2;
#pragma unroll 4
                for (int kk = 0; kk < 64; ++kk) {
                    int k = kc + 8 * kk;
                    unsigned uw = *(const unsigned*)(wb + (size_t)k * V);
                    float wx = __uint_as_float(uw << 16);
                    float wy = __uint_as_float(uw & 0xffff0000u);
                    const float* xp = xs + k * 32;
#pragma unroll
                    for (int q = 0; q < 8; ++q) {
                        f32x4 xv = *(const f32x4*)(xp + ((q * 4) ^ sw));
                        a0[q*4+0] = fmaf(wx, xv.x, a0[q*4+0]); a1[q*4+0] = fmaf(wy, xv.x, a1[q*4+0]);
                        a0[q*4+1] = fmaf(wx, xv.y, a0[q*4+1]); a1[q*4+1] = fmaf(wy, xv.y, a1[q*4+1]);
                        a0[q*4+2] = fmaf(wx, xv.z, a0[q*4+2]); a1[q*4+2] = fmaf(wy, xv.z, a1[q*4+2]);
                        a0[q*4+3] = fmaf(wx, xv.w, a0[q*4+3]); a1[q*4+3] = fmaf(wy, xv.w, a1[q*4+3]);
                    }
                }
            } else {
                const float* wb = WahT + (blk - 500) * 64 + rp2;
#pragma unroll 4
                for (int kk = 0; kk < 64; ++kk) {
                    int k = kc + 8 * kk;
                    float2 w = *(const float2*)(wb + (size_t)k * H2);
                    const float* xp = xs + k * 32;
#pragma unroll
                    for (int q = 0; q < 8; ++q) {
                        f32x4 xv = *(const f32x4*)(xp + ((q * 4) ^ sw));
                        a0[q*4+0] = fmaf(w.x, xv.x, a0[q*4+0]); a1[q*4+0] = fmaf(w.y, xv.x, a1[q*4+0]);
                        a0[q*4+1] = fmaf(w.x, xv.y, a0[q*4+1]); a1[q*4+1] = fmaf(w.y, xv.y, a1[q*4+1]);
                        a0[q*4+2] = fmaf(w.x, xv.z, a0[q*4+2]); a1[q*4+2] = fmaf(w.y, xv.z, a1[q*4+2]);
                        a0[q*4+3] = fmaf(w.x, xv.w, a0[q*4+3]); a1[q*4+3] = fmaf(w.y, xv.w, a1[q*4+3]);
                    }
                }
            }
#pragma unroll
            for (int j = 0; j < 32; ++j) {
                a0[j] += __shfl_xor(a0[j], 8); a0[j] += __shfl_xor(a0[j], 16); a0[j] += __shfl_xor(a0[j], 32);
                a1[j] += __shfl_xor(a1[j], 8); a1[j] += __shfl_xor(a1[j], 16); a1[j] += __shfl_xor(a1[j], 32);
            }
            __syncthreads();   // x-slab free; alias z into xs
            if (!isQ) {
                if (((tid >> 3) & 7) == 0) {
#pragma unroll
                    for (int j = 0; j < 32; ++j) {
                        xs[(rp2    ) * 37 + j] = a0[j];
                        xs[(rp2 + 1) * 37 + j] = a1[j];
                    }
                }
                __syncthreads();
                int row0 = blk * 64;
                {
                    int r = tid & 63, bo = tid >> 6;
                    float bv = bout[row0 + r];
#pragma unroll
                    for (int e = 0; e < 8; ++e) {
                        int b = bo * 8 + e;
                        __builtin_nontemporal_store(xs[r * 37 + b] + bv,
                            out + ((size_t)(b * T) + t) * V + row0 + r);
                    }
                }
                float* pm8 = xs + S0; float* ps8 = pm8 + 256; int* pi8 = (int*)(ps8 + 256);
                {
                    int g = tid >> 5, b = tid & 31;
                    float m = -INFINITY, s = 0.f; int mi = 0;
#pragma unroll
                    for (int i = 0; i < 8; ++i) {
                        int rr = g * 8 + i;
                        float v = xs[rr * 37 + b] + bout[row0 + rr];
                        if (v > m) { s *= __expf(m - v); m = v; mi = row0 + rr; }
                        s += __expf(v - m);
                    }
                    pm8[g * 32 + b] = m; ps8[g * 32 + b] = s; pi8[g * 32 + b] = mi;
                }
                __syncthreads();
                if (tid < 32) {
                    int b = tid;
                    float m = pm8[b], s = ps8[b]; int mi = pi8[b];
#pragma unroll
                    for (int g = 1; g < 8; ++g) {
                        float m2 = pm8[g * 32 + b], s2 = ps8[g * 32 + b]; int i2 = pi8[g * 32 + b];
                        amerge(m, s, mi, m2, s2, i2);
                    }
                    f32x4 pk; pk.x = m; pk.y = s; pk.z = __int_as_float(mi); pk.w = 0.f;
                    AGSTORE(P4 + ((size_t)b * 512 + blk) * 4, pk);
                }
            } else {
                if (((tid >> 3) & 7) == 0) {
                    int j0 = (blk - 500) * 64 + rp2;
#pragma unroll
                    for (int b = 0; b < 32; ++b) {
                        sta(q_buf + b * H2 + j0, a0[b]);
                        sta(q_buf + b * H2 + j0 + 1, a1[b]);
                    }
                }
            }
        }
        ++bgen; gbar(slots, gen, bgen, false, 508);
    }

    // ---------- tail: lse for t = 127
    if (blk < 32) {
        int b = blk;
        float* rm = xs + S0; float* rs = rm + 256;
        float m = -INFINITY, s = 0.f; int mi = 0;
        {
            const float* p0 = P4 + ((size_t)b * 512 + tid) * 4;
            bool has1 = (tid + 256) < 500;
            const float* p1 = has1 ? (p0 + 1024) : p0;
            f32x4 v0, v1;
            AGLOAD(v0, p0); AGLOAD(v1, p1);
            AGWAIT2(v0, v1);
            amerge(m, s, mi, v0.x, v0.y, __float_as_int(v0.z));
            if (has1) amerge(m, s, mi, v1.x, v1.y, __float_as_int(v1.z));
        }
        rm[tid] = m; rs[tid] = s;
        __syncthreads();
        for (int off = 128; off >= 1; off >>= 1) {
            if (tid < off) {
                float m1 = rm[tid], m2 = rm[tid + off];
                float s1 = rs[tid], s2 = rs[tid + off];
                float m_, s_;
                if (m2 > m1)      { m_ = m2; s_ = s2 + s1 * __expf(m1 - m2); }
                else if (m1 > m2) { m_ = m1; s_ = s1 + s2 * __expf(m2 - m1); }
                else              { m_ = m1; s_ = s1 + s2; }
                rm[tid] = m_; rs[tid] = s_;
            }
            __syncthreads();
        }
        if (tid == 0) lse[b * T + (T - 1)] = rm[0] + logf(rs[0]);
    }
}

extern "C" void kernel_launch(void* const* d_in, const int* in_sizes, int n_in,
                              void* d_out, int out_size, void* d_ws, size_t ws_size,
                              hipStream_t stream) {
    const int* x          = (const int*)d_in[0];
    const float* emb_enc  = (const float*)d_in[1];
    const float* Wih_f    = (const float*)d_in[2];
    const float* Whh_f    = (const float*)d_in[3];
    const float* bih_f    = (const float*)d_in[4];
    const float* bhh_f    = (const float*)d_in[5];
    const float* Wih_b    = (const float*)d_in[6];
    const float* Whh_b    = (const float*)d_in[7];
    const float* bih_b    = (const float*)d_in[8];
    const float* bhh_b    = (const float*)d_in[9];
    const float* emb_dec  = (const float*)d_in[10];
    const float* Wa_h     = (const float*)d_in[11];
    const float* Wa_e     = (const float*)d_in[12];
    const float* v_a      = (const float*)d_in[13];
    const float* b_a      = (const float*)d_in[14];
    const float* Wih_d    = (const float*)d_in[15];
    const float* Whh_d    = (const float*)d_in[16];
    const float* bih_d    = (const float*)d_in[17];
    const float* bhh_d    = (const float*)d_in[18];
    const float* Wout     = (const float*)d_in[19];
    const float* bout     = (const float*)d_in[20];
    float* out = (float*)d_out;

    float* ws = (float*)d_ws;
    size_t o = 0;
    float* enc_out = ws + o; o += (size_t)B * T * H2;       // 2,097,152
    float* proj_e  = ws + o; o += (size_t)B * T * H2;       // 2,097,152
    unsigned short* WoutB = (unsigned short*)(ws + o); o += (size_t)H2 * V / 2;  // 8,192,000 floats
    float* WdT     = ws + o; o += (size_t)1280 * 2048;      // 2,621,440
    float* WencT   = ws + o; o += (size_t)512 * 2048;       // 1,048,576
    float* WahT    = ws + o; o += (size_t)H2 * H2;          // 262,144
    float* zpenc   = ws + o; o += 2 * 2 * 2048 * 32;        // 262,144
    float* hdecT   = ws + o; o += 16384;
    float* cdecT   = ws + o; o += 16384;
    float* xcatB   = ws + o; o += 32 * 768;                 // 24,576  [b][768]
    float* q_buf   = ws + o; o += 16384;
    float* zp_h    = ws + o; o += 2048 * 32;                // 65,536
    float* P4      = ws + o; o += (size_t)32 * 512 * 4;     // 65,536
    float* lse     = ws + o; o += 32 * 128;
    int*   slots   = (int*)(ws + o); o += 512 * 32;
    int*   gen     = (int*)(ws + o); o += 8 * 32;

    hipMemsetAsync(slots, 0, (512 * 32 + 8 * 32) * sizeof(int), stream);

    k_trb<<<dim3(1000, 16), 256, 0, stream>>>(Wout, WoutB, V, H2);
    k_tr<<<dim3(16, 16), 256, 0, stream>>>(Wa_h, WahT, H2, H2);
    k_prep_encw<<<4096, 256, 0, stream>>>(Wih_f, Whh_f, Wih_b, Whh_b, WencT);
    k_prep_decw<<<10240, 256, 0, stream>>>(Wih_d, Whh_d, WdT);

    k_seq<<<NBLK, NTHR, LDS_FLOATS * sizeof(float), stream>>>(
        x, emb_enc, emb_dec,
        bih_f, bhh_f, bih_b, bhh_b, bih_d, bhh_d,
        Wa_e, Wa_h, b_a, v_a, bout,
        WencT, WdT, WoutB, WahT,
        enc_out, proj_e, zpenc,
        hdecT, cdecT, xcatB, q_buf, zp_h,
        P4, lse, out, slots, gen);

    k_norm<<<4096, 256, 0, stream>>>(out, lse);
}